// Round 7
// baseline (26911.163 us; speedup 1.0000x reference)
//
#include <hip/hip_runtime.h>
#include <hip/hip_bf16.h>
#include <math.h>

// EndoMamba — correctness baseline. World model (r6-final, all verified):
// inputs fp32, OUTPUT fp32 (harness ref is bf16-rounded => grid-aligned max;
// label "bf16" is generic). in_sizes all match fp32 counts (r6 sentinel run).
// B=2,C=3,T=4,H=W=224,P=16 -> N=196, L=784, M=1568; E=384, Di=768, S=8, R=24.
#define Bn   2
#define Tn   4
#define Nn   196
#define Ln   784
#define Mn   1568
#define En   384
#define Din  768
#define Sn   8
#define Rn   24
#define DEPTH 12
#define NSPA 6

__device__ __forceinline__ float siluf(float v) { return v / (1.f + expf(-v)); }

// 1 ---------------------------------------------- patch embed: thread/(m,e)
__global__ __launch_bounds__(256) void k_embed(
    const float* __restrict__ x, const float* __restrict__ pw,
    const float* __restrict__ pb, const float* __restrict__ pos,
    float* __restrict__ h)
{
    int gid = blockIdx.x*blockDim.x + threadIdx.x;
    if (gid >= Mn*En) return;
    int e = gid % En, token = gid / En;
    int b = token / Ln, l = token % Ln;
    int t = l / Nn, n = l % Nn;
    int hh = n / 14, ww = n % 14;
    float acc = pb[e];
    for (int c = 0; c < 3; ++c)
        for (int p = 0; p < 16; ++p)
            for (int q = 0; q < 16; ++q) {
                float xv = x[(((size_t)(b*3 + c)*Tn + t)*224 + (hh*16 + p))*224 + (ww*16 + q)];
                acc = fmaf(xv, pw[((size_t)(e*3 + c)*16 + p)*16 + q], acc);
            }
    acc += pos[n*En + e];
    float div = expf(-logf(10000.f) * (float)(e & ~1) / (float)En);
    acc += (e & 1) ? cosf((float)t * div) : sinf((float)t * div);
    h[gid] = acc;
}

// 2 -------------------------------------- rmsnorm(+residual): thread/token
__global__ __launch_bounds__(256) void k_rms(
    const float* __restrict__ hin, float* __restrict__ res,
    float* __restrict__ hn, const float* __restrict__ w, int first)
{
    int m = blockIdx.x*blockDim.x + threadIdx.x;
    if (m >= Mn) return;
    const float* hp = hin + (size_t)m*En;
    float* rp = res + (size_t)m*En;
    float ss = 0.f;
    for (int e = 0; e < En; ++e) {
        float r = first ? hp[e] : (hp[e] + rp[e]);
        rp[e] = r;
        ss = fmaf(r, r, ss);
    }
    float sc = rsqrtf(ss * (1.f/(float)En) + 1e-5f);
    for (int e = 0; e < En; ++e)
        hn[(size_t)m*En + e] = rp[e] * sc * w[e];
}

// 3 ----------------------------------- in_proj: thread/(m,f), f<1536, K=384
__global__ __launch_bounds__(256) void k_inproj(
    const float* __restrict__ hn, const float* __restrict__ W,
    float* __restrict__ xz)
{
    int gid = blockIdx.x*blockDim.x + threadIdx.x;
    if (gid >= Mn*1536) return;
    int f = gid % 1536, m = gid / 1536;
    const float* a = hn + (size_t)m*En;
    const float* w = W + (size_t)f*En;
    float acc = 0.f;
    for (int k = 0; k < En; ++k) acc = fmaf(a[k], w[k], acc);
    xz[(size_t)m*1536 + f] = acc;
}

// 4 ------------------------- causal depthwise conv + silu: thread/(b,l,d)
__global__ __launch_bounds__(256) void k_conv(
    const float* __restrict__ xz, const float* __restrict__ cw,
    const float* __restrict__ cb, float* __restrict__ xc, int reverse)
{
    int gid = blockIdx.x*blockDim.x + threadIdx.x;
    if (gid >= Mn*Din) return;
    int d = gid % Din, m = gid / Din;
    int l = m % Ln, b = m / Ln;
    float acc = cb[d];
    for (int k = 0; k < 4; ++k) {
        int ls = l - 3 + k;
        if (ls < 0) continue;
        int lsrc = reverse ? (Ln - 1 - ls) : ls;
        acc = fmaf(xz[(size_t)(b*Ln + lsrc)*1536 + d], cw[d*4 + k], acc);
    }
    xc[gid] = siluf(acc);
}

// 5 ----------------------------------- xproj: thread/(m,e), e<40, K=768
__global__ __launch_bounds__(256) void k_xproj(
    const float* __restrict__ xc, const float* __restrict__ xw,
    float* __restrict__ xd)
{
    int gid = blockIdx.x*blockDim.x + threadIdx.x;
    if (gid >= Mn*40) return;
    int e = gid % 40, m = gid / 40;
    const float* a = xc + (size_t)m*Din;
    const float* w = xw + (size_t)e*Din;
    float acc = 0.f;
    for (int k = 0; k < Din; ++k) acc = fmaf(a[k], w[k], acc);
    xd[(size_t)m*40 + e] = acc;
}

// 6 ------------------------- dtproj + softplus: thread/(m,d), K=24
__global__ __launch_bounds__(256) void k_dtproj(
    const float* __restrict__ xd, const float* __restrict__ dw,
    const float* __restrict__ db, float* __restrict__ dt)
{
    int gid = blockIdx.x*blockDim.x + threadIdx.x;
    if (gid >= Mn*Din) return;
    int d = gid % Din, m = gid / Din;
    const float* r = xd + (size_t)m*40;
    const float* w = dw + (size_t)d*Rn;
    float acc = db[d];
    for (int k = 0; k < Rn; ++k) acc = fmaf(r[k], w[k], acc);
    dt[gid] = (acc > 20.f) ? acc : log1pf(expf(acc));
}

// 7 ---------------------- selective scan: thread/(b,d), 8 states in regs
__global__ __launch_bounds__(256) void k_scan(
    const float* __restrict__ u, const float* __restrict__ dt,
    const float* __restrict__ xd, const float* __restrict__ A_log,
    const float* __restrict__ Dp, float* __restrict__ y,
    int reverse, int accum)
{
    int gid = blockIdx.x*blockDim.x + threadIdx.x;
    if (gid >= Bn*Din) return;
    int d = gid % Din, b = gid / Din;
    float A[Sn], hs[Sn];
    for (int s = 0; s < Sn; ++s) { A[s] = -expf(A_log[d*Sn + s]); hs[s] = 0.f; }
    float Dd = Dp[d];
    for (int l = 0; l < Ln; ++l) {
        size_t mrow = (size_t)(b*Ln + l);
        float dtv = dt[mrow*Din + d];
        float uv  = u [mrow*Din + d];
        const float* xr = xd + mrow*40;
        float yv = 0.f;
        #pragma unroll
        for (int s = 0; s < Sn; ++s) {
            hs[s] = fmaf(expf(dtv * A[s]), hs[s], dtv * uv * xr[Rn + s]);
            yv = fmaf(hs[s], xr[Rn + Sn + s], yv);
        }
        yv = fmaf(uv, Dd, yv);
        int ol = reverse ? (Ln - 1 - l) : l;
        float* dst = y + (size_t)(b*Ln + ol)*Din + d;
        if (accum) *dst += yv; else *dst = yv;
    }
}

// 8 ------------------- out_proj with silu(z) gate: thread/(m,e), K=768
__global__ __launch_bounds__(256) void k_outproj(
    const float* __restrict__ yt, const float* __restrict__ xz,
    const float* __restrict__ W, float* __restrict__ h)
{
    int gid = blockIdx.x*blockDim.x + threadIdx.x;
    if (gid >= Mn*En) return;
    int e = gid % En, m = gid / En;
    const float* yr = yt + (size_t)m*Din;
    const float* zr = xz + (size_t)m*1536 + Din;
    const float* w  = W + (size_t)e*Din;
    float acc = 0.f;
    for (int i = 0; i < Din; ++i)
        acc = fmaf(yr[i] * siluf(zr[i]), w[i], acc);
    h[gid] = acc;
}

// 9 --------------------------------------- final rmsnorm -> FP32 out
__global__ __launch_bounds__(256) void k_final(
    const float* __restrict__ h, const float* __restrict__ res,
    const float* __restrict__ w, float* __restrict__ out)
{
    int m = blockIdx.x*blockDim.x + threadIdx.x;
    if (m >= Mn) return;
    const float* hp = h + (size_t)m*En;
    const float* rp = res + (size_t)m*En;
    float ss = 0.f;
    for (int e = 0; e < En; ++e) {
        float r = hp[e] + rp[e];
        ss = fmaf(r, r, ss);
    }
    float sc = rsqrtf(ss * (1.f/(float)En) + 1e-5f);
    for (int e = 0; e < En; ++e)
        out[(size_t)m*En + e] = (hp[e] + rp[e]) * sc * w[e];
}

extern "C" void kernel_launch(void* const* d_in, const int* in_sizes, int n_in,
                              void* d_out, int out_size, void* d_ws, size_t ws_size,
                              hipStream_t stream)
{
    const float* x         = (const float*)d_in[0];
    const float* patch_w   = (const float*)d_in[1];
    const float* patch_b   = (const float*)d_in[2];
    const float* pos_embed = (const float*)d_in[3];
    const float* in_proj_w = (const float*)d_in[4];
    const float* conv_w    = (const float*)d_in[5];
    const float* conv_b    = (const float*)d_in[6];
    const float* xproj_w   = (const float*)d_in[7];
    const float* dtproj_w  = (const float*)d_in[8];
    const float* dtproj_b  = (const float*)d_in[9];
    const float* A_log     = (const float*)d_in[10];
    const float* D_param   = (const float*)d_in[11];
    const float* outproj_w = (const float*)d_in[12];
    const float* norm_w    = (const float*)d_in[13];
    const float* conv_wb   = (const float*)d_in[14];
    const float* conv_bb   = (const float*)d_in[15];
    const float* xproj_wb  = (const float*)d_in[16];
    const float* dtproj_wb = (const float*)d_in[17];
    const float* dtproj_bb = (const float*)d_in[18];
    const float* A_log_b   = (const float*)d_in[19];
    const float* D_b       = (const float*)d_in[20];
    const float* norm_f_w  = (const float*)d_in[21];

    // flat fp32 carve, no overlays: 7,890,176 floats = 30.1 MB
    float* p   = (float*)d_ws;
    float* h   = p;  p += (size_t)Mn*En;
    float* res = p;  p += (size_t)Mn*En;
    float* hn  = p;  p += (size_t)Mn*En;
    float* xz  = p;  p += (size_t)Mn*1536;
    float* xc  = p;  p += (size_t)Mn*Din;
    float* xd  = p;  p += (size_t)Mn*40;
    float* dt  = p;  p += (size_t)Mn*Din;
    float* yt  = p;  p += (size_t)Mn*Din;
    size_t needed = (size_t)(p - (float*)d_ws) * sizeof(float);
    if (ws_size < needed) return;

    const int B_me  = (Mn*En   + 255)/256;   // 2352
    const int B_m   = (Mn      + 255)/256;   // 7
    const int B_mf  = (Mn*1536 + 255)/256;   // 9408
    const int B_md  = (Mn*Din  + 255)/256;   // 4704
    const int B_m40 = (Mn*40   + 255)/256;   // 245
    const int B_bd  = (Bn*Din  + 255)/256;   // 6

    k_embed<<<B_me, 256, 0, stream>>>(x, patch_w, patch_b, pos_embed, h);

    for (int i = 0; i < DEPTH; ++i) {
        k_rms<<<B_m, 256, 0, stream>>>(h, res, hn, norm_w + (size_t)i*En, i == 0);
        k_inproj<<<B_mf, 256, 0, stream>>>(hn, in_proj_w + (size_t)i*1536*En, xz);

        k_conv<<<B_md, 256, 0, stream>>>(xz, conv_w + (size_t)i*Din*4,
                                         conv_b + (size_t)i*Din, xc, 0);
        k_xproj<<<B_m40, 256, 0, stream>>>(xc, xproj_w + (size_t)i*40*Din, xd);
        k_dtproj<<<B_md, 256, 0, stream>>>(xd, dtproj_w + (size_t)i*Din*Rn,
                                           dtproj_b + (size_t)i*Din, dt);
        k_scan<<<B_bd, 256, 0, stream>>>(xc, dt, xd, A_log + (size_t)i*Din*Sn,
                                         D_param + (size_t)i*Din, yt, 0, 0);

        if (i < NSPA) {
            k_conv<<<B_md, 256, 0, stream>>>(xz, conv_wb + (size_t)i*Din*4,
                                             conv_bb + (size_t)i*Din, xc, 1);
            k_xproj<<<B_m40, 256, 0, stream>>>(xc, xproj_wb + (size_t)i*40*Din, xd);
            k_dtproj<<<B_md, 256, 0, stream>>>(xd, dtproj_wb + (size_t)i*Din*Rn,
                                               dtproj_bb + (size_t)i*Din, dt);
            k_scan<<<B_bd, 256, 0, stream>>>(xc, dt, xd, A_log_b + (size_t)i*Din*Sn,
                                             D_b + (size_t)i*Din, yt, 1, 1);
        }

        k_outproj<<<B_me, 256, 0, stream>>>(yt, xz, outproj_w + (size_t)i*En*Din, h);
    }

    k_final<<<B_m, 256, 0, stream>>>(h, res, norm_f_w, (float*)d_out);
}

// Round 9
// 8885.799 us; speedup vs baseline: 3.0286x; 3.0286x over previous
//
#include <hip/hip_runtime.h>
#include <hip/hip_bf16.h>
#include <math.h>

// EndoMamba r9: r8 + grid fix — GEMM m-grid must be ceil(M/64)=25, not 24
// (r8's Mn/64 dropped tokens 1536..1567 => absmax 0.172 = layer contribution).
// Inputs fp32, output fp32. M=1568; E=384, Di=768, S=8, R=24.
#define Bn   2
#define Tn   4
#define Nn   196
#define Ln   784
#define Mn   1568
#define En   384
#define Din  768
#define Sn   8
#define Rn   24
#define DEPTH 12
#define NSPA 6

__device__ __forceinline__ float siluf(float v) { return v / (1.f + __expf(-v)); }

// ---------------------------------------------------------------- patch embed
__global__ __launch_bounds__(256) void patch_embed(
    const float* __restrict__ x, const float* __restrict__ pw,
    const float* __restrict__ pb, const float* __restrict__ pos,
    float* __restrict__ h)
{
    int token = blockIdx.x;              // b*784 + t*196 + n
    int b = token / Ln;  int l = token % Ln;
    int t = l / Nn;      int n = l % Nn;
    int hh = n / 14, ww = n % 14;
    __shared__ float patch[768];
    for (int idx = threadIdx.x; idx < 768; idx += blockDim.x) {
        int c = idx >> 8; int rem = idx & 255; int p = rem >> 4; int q = rem & 15;
        patch[idx] = x[(((size_t)(b*3 + c)*Tn + t)*224 + (hh*16 + p))*224 + (ww*16 + q)];
    }
    __syncthreads();
    for (int e = threadIdx.x; e < En; e += blockDim.x) {
        const float* w = pw + (size_t)e * 768;
        float acc = pb[e];
        #pragma unroll 4
        for (int k = 0; k < 768; k += 4) {
            float4 wv = *(const float4*)(w + k);
            acc = fmaf(patch[k+0], wv.x, acc);
            acc = fmaf(patch[k+1], wv.y, acc);
            acc = fmaf(patch[k+2], wv.z, acc);
            acc = fmaf(patch[k+3], wv.w, acc);
        }
        acc += pos[n*En + e];
        float div = expf(-logf(10000.f) * (float)(e & ~1) / (float)En);
        float ang = (float)t * div;
        acc += (e & 1) ? cosf(ang) : sinf(ang);
        h[(size_t)token*En + e] = acc;
    }
}

// ------------------------------------------------------- rmsnorm (+ residual)
__global__ __launch_bounds__(256) void rms_residual(
    const float* __restrict__ hin, float* __restrict__ res,
    float* __restrict__ hn, const float* __restrict__ w, int first)
{
    int wid  = (blockIdx.x * blockDim.x + threadIdx.x) >> 6;   // token
    int lane = threadIdx.x & 63;
    if (wid >= Mn) return;
    const float* hp = hin + (size_t)wid*En;
    float* rp = res + (size_t)wid*En;
    float v[6]; float ss = 0.f;
    #pragma unroll
    for (int j = 0; j < 6; ++j) {
        int e = lane + j*64;
        float r = first ? hp[e] : (hp[e] + rp[e]);
        v[j] = r; ss = fmaf(r, r, ss);
    }
    #pragma unroll
    for (int off = 32; off; off >>= 1) ss += __shfl_xor(ss, off, 64);
    float scale = rsqrtf(ss * (1.f/(float)En) + 1e-5f);
    #pragma unroll
    for (int j = 0; j < 6; ++j) {
        int e = lane + j*64;
        rp[e] = v[j];
        hn[(size_t)wid*En + e] = v[j] * scale * w[e];
    }
}

// --------------------------------------------------- fp32 tiled GEMM C=A*W^T
// A:[M,K] lda. W:[N,K]. GATE: A_eff = A*silu(Z). 64x64 tile, 4x4/thread.
template<int GATE>
__global__ __launch_bounds__(256) void gemm64(
    const float* __restrict__ A, int lda,
    const float* __restrict__ W,
    const float* __restrict__ Z, int ldz,
    float* __restrict__ C, int ldc,
    int M, int N, int K)
{
    __shared__ float As[16][64];
    __shared__ float Bs[16][64];
    int n0 = blockIdx.x * 64;
    int m0 = blockIdx.y * 64;
    int tid = threadIdx.x;
    int tx = tid & 15, ty = tid >> 4;
    int lrow = tid >> 2;            // 0..63
    int lk   = (tid & 3) << 2;      // 0,4,8,12
    float acc[4][4] = {};
    for (int k0 = 0; k0 < K; k0 += 16) {
        int mg = m0 + lrow; if (mg >= M) mg = M - 1;   // clamp: partial m-tile
        float4 av = *(const float4*)(A + (size_t)mg*lda + (k0 + lk));
        if (GATE) {
            float4 zv = *(const float4*)(Z + (size_t)mg*ldz + (k0 + lk));
            av.x *= siluf(zv.x);
            av.y *= siluf(zv.y);
            av.z *= siluf(zv.z);
            av.w *= siluf(zv.w);
        }
        float4 wv = *(const float4*)(W + (size_t)(n0 + lrow)*K + (k0 + lk));
        __syncthreads();
        As[lk+0][lrow]=av.x; As[lk+1][lrow]=av.y; As[lk+2][lrow]=av.z; As[lk+3][lrow]=av.w;
        Bs[lk+0][lrow]=wv.x; Bs[lk+1][lrow]=wv.y; Bs[lk+2][lrow]=wv.z; Bs[lk+3][lrow]=wv.w;
        __syncthreads();
        #pragma unroll
        for (int kk = 0; kk < 16; ++kk) {
            float4 a = *(const float4*)&As[kk][ty<<2];
            float4 b = *(const float4*)&Bs[kk][tx<<2];
            acc[0][0]=fmaf(a.x,b.x,acc[0][0]); acc[0][1]=fmaf(a.x,b.y,acc[0][1]);
            acc[0][2]=fmaf(a.x,b.z,acc[0][2]); acc[0][3]=fmaf(a.x,b.w,acc[0][3]);
            acc[1][0]=fmaf(a.y,b.x,acc[1][0]); acc[1][1]=fmaf(a.y,b.y,acc[1][1]);
            acc[1][2]=fmaf(a.y,b.z,acc[1][2]); acc[1][3]=fmaf(a.y,b.w,acc[1][3]);
            acc[2][0]=fmaf(a.z,b.x,acc[2][0]); acc[2][1]=fmaf(a.z,b.y,acc[2][1]);
            acc[2][2]=fmaf(a.z,b.z,acc[2][2]); acc[2][3]=fmaf(a.z,b.w,acc[2][3]);
            acc[3][0]=fmaf(a.w,b.x,acc[3][0]); acc[3][1]=fmaf(a.w,b.y,acc[3][1]);
            acc[3][2]=fmaf(a.w,b.z,acc[3][2]); acc[3][3]=fmaf(a.w,b.w,acc[3][3]);
        }
    }
    #pragma unroll
    for (int i = 0; i < 4; ++i) {
        int mg = m0 + (ty<<2) + i;
        if (mg < M) {
            float* cp = C + (size_t)mg*ldc + n0 + (tx<<2);
            cp[0]=acc[i][0]; cp[1]=acc[i][1]; cp[2]=acc[i][2]; cp[3]=acc[i][3];
        }
    }
}

// ------------------------------------------------- causal depthwise conv+silu
__global__ __launch_bounds__(256) void k_conv(
    const float* __restrict__ xz, const float* __restrict__ cw,
    const float* __restrict__ cb, float* __restrict__ xc, int reverse)
{
    int gid = blockIdx.x*blockDim.x + threadIdx.x;
    if (gid >= Mn*Din) return;
    int d = gid % Din, m = gid / Din;
    int l = m % Ln, b = m / Ln;
    float acc = cb[d];
    #pragma unroll
    for (int k = 0; k < 4; ++k) {
        int ls = l - 3 + k;
        if (ls < 0) continue;
        int lsrc = reverse ? (Ln - 1 - ls) : ls;
        acc = fmaf(xz[(size_t)(b*Ln + lsrc)*1536 + d], cw[d*4 + k], acc);
    }
    xc[gid] = siluf(acc);
}

// ------------------------------------------------------- xproj: 768 -> 40
__global__ __launch_bounds__(256) void xproj_k(
    const float* __restrict__ xc, const float* __restrict__ xw,
    float* __restrict__ xd)
{
    int wid  = (blockIdx.x*blockDim.x + threadIdx.x) >> 6;
    int lane = threadIdx.x & 63;
    if (wid >= Mn) return;
    const float* xr = xc + (size_t)wid*Din;
    float v[12];
    #pragma unroll
    for (int j = 0; j < 12; ++j) v[j] = xr[lane + j*64];
    for (int e = 0; e < Rn + 2*Sn; ++e) {
        const float* wr = xw + (size_t)e*Din;
        float acc = 0.f;
        #pragma unroll
        for (int j = 0; j < 12; ++j) acc = fmaf(v[j], wr[lane + j*64], acc);
        #pragma unroll
        for (int off = 32; off; off >>= 1) acc += __shfl_xor(acc, off, 64);
        if (lane == 0) xd[(size_t)wid*40 + e] = acc;
    }
}

// ---------------------------------------------- dtproj (24->768) + softplus
__global__ __launch_bounds__(256) void k_dtproj(
    const float* __restrict__ xd, const float* __restrict__ dw,
    const float* __restrict__ db, float* __restrict__ dt)
{
    int gid = blockIdx.x*blockDim.x + threadIdx.x;
    if (gid >= Mn*Din) return;
    int d = gid % Din, m = gid / Din;
    const float* r = xd + (size_t)m*40;
    const float* w = dw + (size_t)d*Rn;
    float acc = db[d];
    #pragma unroll
    for (int k = 0; k < Rn; ++k) acc = fmaf(r[k], w[k], acc);
    dt[gid] = (acc > 20.f) ? acc : log1pf(__expf(acc));
}

// ---------------------- selective scan: thread/(b,d), 8 states, unroll 8
__global__ __launch_bounds__(256) void k_scan(
    const float* __restrict__ u, const float* __restrict__ dt,
    const float* __restrict__ xd, const float* __restrict__ A_log,
    const float* __restrict__ Dp, float* __restrict__ y,
    int reverse, int accum)
{
    int gid = blockIdx.x*blockDim.x + threadIdx.x;
    if (gid >= Bn*Din) return;
    int d = gid % Din, b = gid / Din;
    float A[Sn], hs[Sn];
    #pragma unroll
    for (int s = 0; s < Sn; ++s) { A[s] = -__expf(A_log[d*Sn + s]); hs[s] = 0.f; }
    float Dd = Dp[d];
    const float* up  = u  + (size_t)b*Ln*Din + d;
    const float* dtp = dt + (size_t)b*Ln*Din + d;
    const float* xp  = xd + (size_t)b*Ln*40;
    float* yp = y + (size_t)b*Ln*Din + d;
    #pragma unroll 8
    for (int l = 0; l < Ln; ++l) {
        float dtv = dtp[(size_t)l*Din];
        float uv  = up [(size_t)l*Din];
        const float4* xr4 = (const float4*)(xp + l*40 + Rn);
        float4 Bv0 = xr4[0], Bv1 = xr4[1], Cv0 = xr4[2], Cv1 = xr4[3];
        float du = dtv * uv;
        float yv = 0.f;
        hs[0] = fmaf(__expf(dtv*A[0]), hs[0], du*Bv0.x); yv = fmaf(hs[0], Cv0.x, yv);
        hs[1] = fmaf(__expf(dtv*A[1]), hs[1], du*Bv0.y); yv = fmaf(hs[1], Cv0.y, yv);
        hs[2] = fmaf(__expf(dtv*A[2]), hs[2], du*Bv0.z); yv = fmaf(hs[2], Cv0.z, yv);
        hs[3] = fmaf(__expf(dtv*A[3]), hs[3], du*Bv0.w); yv = fmaf(hs[3], Cv0.w, yv);
        hs[4] = fmaf(__expf(dtv*A[4]), hs[4], du*Bv1.x); yv = fmaf(hs[4], Cv1.x, yv);
        hs[5] = fmaf(__expf(dtv*A[5]), hs[5], du*Bv1.y); yv = fmaf(hs[5], Cv1.y, yv);
        hs[6] = fmaf(__expf(dtv*A[6]), hs[6], du*Bv1.z); yv = fmaf(hs[6], Cv1.z, yv);
        hs[7] = fmaf(__expf(dtv*A[7]), hs[7], du*Bv1.w); yv = fmaf(hs[7], Cv1.w, yv);
        yv = fmaf(uv, Dd, yv);
        int ol = reverse ? (Ln - 1 - l) : l;
        float* dst = yp + (size_t)ol*Din;
        if (accum) *dst += yv; else *dst = yv;
    }
}

// ------------------------------------------------------------- final rmsnorm
__global__ __launch_bounds__(256) void final_k(
    const float* __restrict__ h, const float* __restrict__ res,
    const float* __restrict__ w, float* __restrict__ out)
{
    int wid  = (blockIdx.x * blockDim.x + threadIdx.x) >> 6;
    int lane = threadIdx.x & 63;
    if (wid >= Mn) return;
    const float* hp = h + (size_t)wid*En;
    const float* rp = res + (size_t)wid*En;
    float v[6]; float ss = 0.f;
    #pragma unroll
    for (int j = 0; j < 6; ++j) {
        int e = lane + j*64;
        float r = hp[e] + rp[e];
        v[j] = r; ss = fmaf(r, r, ss);
    }
    #pragma unroll
    for (int off = 32; off; off >>= 1) ss += __shfl_xor(ss, off, 64);
    float scale = rsqrtf(ss * (1.f/(float)En) + 1e-5f);
    #pragma unroll
    for (int j = 0; j < 6; ++j) {
        int e = lane + j*64;
        out[(size_t)wid*En + e] = v[j] * scale * w[e];
    }
}

extern "C" void kernel_launch(void* const* d_in, const int* in_sizes, int n_in,
                              void* d_out, int out_size, void* d_ws, size_t ws_size,
                              hipStream_t stream)
{
    const float* x         = (const float*)d_in[0];
    const float* patch_w   = (const float*)d_in[1];
    const float* patch_b   = (const float*)d_in[2];
    const float* pos_embed = (const float*)d_in[3];
    const float* in_proj_w = (const float*)d_in[4];
    const float* conv_w    = (const float*)d_in[5];
    const float* conv_b    = (const float*)d_in[6];
    const float* xproj_w   = (const float*)d_in[7];
    const float* dtproj_w  = (const float*)d_in[8];
    const float* dtproj_b  = (const float*)d_in[9];
    const float* A_log     = (const float*)d_in[10];
    const float* D_param   = (const float*)d_in[11];
    const float* outproj_w = (const float*)d_in[12];
    const float* norm_w    = (const float*)d_in[13];
    const float* conv_wb   = (const float*)d_in[14];
    const float* conv_bb   = (const float*)d_in[15];
    const float* xproj_wb  = (const float*)d_in[16];
    const float* dtproj_wb = (const float*)d_in[17];
    const float* dtproj_bb = (const float*)d_in[18];
    const float* A_log_b   = (const float*)d_in[19];
    const float* D_b       = (const float*)d_in[20];
    const float* norm_f_w  = (const float*)d_in[21];

    // flat fp32 carve: 30.1 MB
    float* p   = (float*)d_ws;
    float* h   = p;  p += (size_t)Mn*En;
    float* res = p;  p += (size_t)Mn*En;
    float* hn  = p;  p += (size_t)Mn*En;
    float* xz  = p;  p += (size_t)Mn*1536;
    float* xc  = p;  p += (size_t)Mn*Din;
    float* xd  = p;  p += (size_t)Mn*40;
    float* dt  = p;  p += (size_t)Mn*Din;
    float* yt  = p;  p += (size_t)Mn*Din;
    size_t needed = (size_t)(p - (float*)d_ws) * sizeof(float);
    if (ws_size < needed) return;

    const int wave_blocks = (Mn*64)/256;             // 392
    const int B_md  = (Mn*Din + 255)/256;            // 4704
    const int B_bd  = (Bn*Din + 255)/256;            // 6
    const int mTiles = (Mn + 63)/64;                 // 25 — ceil! (r8 bug: 24)

    patch_embed<<<Mn, 256, 0, stream>>>(x, patch_w, patch_b, pos_embed, h);

    for (int i = 0; i < DEPTH; ++i) {
        rms_residual<<<wave_blocks, 256, 0, stream>>>(h, res, hn, norm_w + (size_t)i*En, i == 0);

        dim3 g1(1536/64, mTiles);
        gemm64<0><<<g1, 256, 0, stream>>>(hn, En, in_proj_w + (size_t)i*1536*En,
                                          nullptr, 0, xz, 1536, Mn, 1536, En);

        k_conv<<<B_md, 256, 0, stream>>>(xz, conv_w + (size_t)i*Din*4,
                                         conv_b + (size_t)i*Din, xc, 0);
        xproj_k<<<wave_blocks, 256, 0, stream>>>(xc, xproj_w + (size_t)i*40*Din, xd);
        k_dtproj<<<B_md, 256, 0, stream>>>(xd, dtproj_w + (size_t)i*Din*Rn,
                                           dtproj_b + (size_t)i*Din, dt);
        k_scan<<<B_bd, 256, 0, stream>>>(xc, dt, xd, A_log + (size_t)i*Din*Sn,
                                         D_param + (size_t)i*Din, yt, 0, 0);

        if (i < NSPA) {
            k_conv<<<B_md, 256, 0, stream>>>(xz, conv_wb + (size_t)i*Din*4,
                                             conv_bb + (size_t)i*Din, xc, 1);
            xproj_k<<<wave_blocks, 256, 0, stream>>>(xc, xproj_wb + (size_t)i*40*Din, xd);
            k_dtproj<<<B_md, 256, 0, stream>>>(xd, dtproj_wb + (size_t)i*Din*Rn,
                                               dtproj_bb + (size_t)i*Din, dt);
            k_scan<<<B_bd, 256, 0, stream>>>(xc, dt, xd, A_log_b + (size_t)i*Din*Sn,
                                             D_b + (size_t)i*Din, yt, 1, 1);
        }

        dim3 g2(En/64, mTiles);
        gemm64<1><<<g2, 256, 0, stream>>>(yt, Din, outproj_w + (size_t)i*En*Din,
                                          xz + Din, 1536, h, En, Mn, En, Din);
    }

    final_k<<<wave_blocks, 256, 0, stream>>>(h, res, norm_f_w, (float*)d_out);
}

// Round 10
// 3327.699 us; speedup vs baseline: 8.0870x; 2.6703x over previous
//
#include <hip/hip_runtime.h>
#include <hip/hip_bf16.h>
#include <math.h>

// EndoMamba r10: chunked parallel scan (16 chunks x 49 steps, 3-phase).
// r9 scan was 6 blocks = 24 waves on 256 CUs -> 523us latency-bound; this
// gives 96 blocks/phase. Inputs fp32, output fp32.
#define Bn   2
#define Tn   4
#define Nn   196
#define Ln   784
#define Mn   1568
#define En   384
#define Din  768
#define Sn   8
#define Rn   24
#define DEPTH 12
#define NSPA 6
#define NC   16
#define CL   49     // 784 = 16*49

__device__ __forceinline__ float siluf(float v) { return v / (1.f + __expf(-v)); }

// ---------------------------------------------------------------- patch embed
__global__ __launch_bounds__(256) void patch_embed(
    const float* __restrict__ x, const float* __restrict__ pw,
    const float* __restrict__ pb, const float* __restrict__ pos,
    float* __restrict__ h)
{
    int token = blockIdx.x;              // b*784 + t*196 + n
    int b = token / Ln;  int l = token % Ln;
    int t = l / Nn;      int n = l % Nn;
    int hh = n / 14, ww = n % 14;
    __shared__ float patch[768];
    for (int idx = threadIdx.x; idx < 768; idx += blockDim.x) {
        int c = idx >> 8; int rem = idx & 255; int p = rem >> 4; int q = rem & 15;
        patch[idx] = x[(((size_t)(b*3 + c)*Tn + t)*224 + (hh*16 + p))*224 + (ww*16 + q)];
    }
    __syncthreads();
    for (int e = threadIdx.x; e < En; e += blockDim.x) {
        const float* w = pw + (size_t)e * 768;
        float acc = pb[e];
        #pragma unroll 4
        for (int k = 0; k < 768; k += 4) {
            float4 wv = *(const float4*)(w + k);
            acc = fmaf(patch[k+0], wv.x, acc);
            acc = fmaf(patch[k+1], wv.y, acc);
            acc = fmaf(patch[k+2], wv.z, acc);
            acc = fmaf(patch[k+3], wv.w, acc);
        }
        acc += pos[n*En + e];
        float div = expf(-logf(10000.f) * (float)(e & ~1) / (float)En);
        float ang = (float)t * div;
        acc += (e & 1) ? cosf(ang) : sinf(ang);
        h[(size_t)token*En + e] = acc;
    }
}

// ------------------------------------------------------- rmsnorm (+ residual)
__global__ __launch_bounds__(256) void rms_residual(
    const float* __restrict__ hin, float* __restrict__ res,
    float* __restrict__ hn, const float* __restrict__ w, int first)
{
    int wid  = (blockIdx.x * blockDim.x + threadIdx.x) >> 6;   // token
    int lane = threadIdx.x & 63;
    if (wid >= Mn) return;
    const float* hp = hin + (size_t)wid*En;
    float* rp = res + (size_t)wid*En;
    float v[6]; float ss = 0.f;
    #pragma unroll
    for (int j = 0; j < 6; ++j) {
        int e = lane + j*64;
        float r = first ? hp[e] : (hp[e] + rp[e]);
        v[j] = r; ss = fmaf(r, r, ss);
    }
    #pragma unroll
    for (int off = 32; off; off >>= 1) ss += __shfl_xor(ss, off, 64);
    float scale = rsqrtf(ss * (1.f/(float)En) + 1e-5f);
    #pragma unroll
    for (int j = 0; j < 6; ++j) {
        int e = lane + j*64;
        rp[e] = v[j];
        hn[(size_t)wid*En + e] = v[j] * scale * w[e];
    }
}

// --------------------------------------------------- fp32 tiled GEMM C=A*W^T
template<int GATE>
__global__ __launch_bounds__(256) void gemm64(
    const float* __restrict__ A, int lda,
    const float* __restrict__ W,
    const float* __restrict__ Z, int ldz,
    float* __restrict__ C, int ldc,
    int M, int N, int K)
{
    __shared__ float As[16][64];
    __shared__ float Bs[16][64];
    int n0 = blockIdx.x * 64;
    int m0 = blockIdx.y * 64;
    int tid = threadIdx.x;
    int tx = tid & 15, ty = tid >> 4;
    int lrow = tid >> 2;            // 0..63
    int lk   = (tid & 3) << 2;      // 0,4,8,12
    float acc[4][4] = {};
    for (int k0 = 0; k0 < K; k0 += 16) {
        int mg = m0 + lrow; if (mg >= M) mg = M - 1;   // clamp: partial m-tile
        float4 av = *(const float4*)(A + (size_t)mg*lda + (k0 + lk));
        if (GATE) {
            float4 zv = *(const float4*)(Z + (size_t)mg*ldz + (k0 + lk));
            av.x *= siluf(zv.x);
            av.y *= siluf(zv.y);
            av.z *= siluf(zv.z);
            av.w *= siluf(zv.w);
        }
        float4 wv = *(const float4*)(W + (size_t)(n0 + lrow)*K + (k0 + lk));
        __syncthreads();
        As[lk+0][lrow]=av.x; As[lk+1][lrow]=av.y; As[lk+2][lrow]=av.z; As[lk+3][lrow]=av.w;
        Bs[lk+0][lrow]=wv.x; Bs[lk+1][lrow]=wv.y; Bs[lk+2][lrow]=wv.z; Bs[lk+3][lrow]=wv.w;
        __syncthreads();
        #pragma unroll
        for (int kk = 0; kk < 16; ++kk) {
            float4 a = *(const float4*)&As[kk][ty<<2];
            float4 b = *(const float4*)&Bs[kk][tx<<2];
            acc[0][0]=fmaf(a.x,b.x,acc[0][0]); acc[0][1]=fmaf(a.x,b.y,acc[0][1]);
            acc[0][2]=fmaf(a.x,b.z,acc[0][2]); acc[0][3]=fmaf(a.x,b.w,acc[0][3]);
            acc[1][0]=fmaf(a.y,b.x,acc[1][0]); acc[1][1]=fmaf(a.y,b.y,acc[1][1]);
            acc[1][2]=fmaf(a.y,b.z,acc[1][2]); acc[1][3]=fmaf(a.y,b.w,acc[1][3]);
            acc[2][0]=fmaf(a.z,b.x,acc[2][0]); acc[2][1]=fmaf(a.z,b.y,acc[2][1]);
            acc[2][2]=fmaf(a.z,b.z,acc[2][2]); acc[2][3]=fmaf(a.z,b.w,acc[2][3]);
            acc[3][0]=fmaf(a.w,b.x,acc[3][0]); acc[3][1]=fmaf(a.w,b.y,acc[3][1]);
            acc[3][2]=fmaf(a.w,b.z,acc[3][2]); acc[3][3]=fmaf(a.w,b.w,acc[3][3]);
        }
    }
    #pragma unroll
    for (int i = 0; i < 4; ++i) {
        int mg = m0 + (ty<<2) + i;
        if (mg < M) {
            float* cp = C + (size_t)mg*ldc + n0 + (tx<<2);
            cp[0]=acc[i][0]; cp[1]=acc[i][1]; cp[2]=acc[i][2]; cp[3]=acc[i][3];
        }
    }
}

// ------------------------------------------------- causal depthwise conv+silu
__global__ __launch_bounds__(256) void k_conv(
    const float* __restrict__ xz, const float* __restrict__ cw,
    const float* __restrict__ cb, float* __restrict__ xc, int reverse)
{
    int gid = blockIdx.x*blockDim.x + threadIdx.x;
    if (gid >= Mn*Din) return;
    int d = gid % Din, m = gid / Din;
    int l = m % Ln, b = m / Ln;
    float acc = cb[d];
    #pragma unroll
    for (int k = 0; k < 4; ++k) {
        int ls = l - 3 + k;
        if (ls < 0) continue;
        int lsrc = reverse ? (Ln - 1 - ls) : ls;
        acc = fmaf(xz[(size_t)(b*Ln + lsrc)*1536 + d], cw[d*4 + k], acc);
    }
    xc[gid] = siluf(acc);
}

// ------------------------------------------------------- xproj: 768 -> 40
__global__ __launch_bounds__(256) void xproj_k(
    const float* __restrict__ xc, const float* __restrict__ xw,
    float* __restrict__ xd)
{
    int wid  = (blockIdx.x*blockDim.x + threadIdx.x) >> 6;
    int lane = threadIdx.x & 63;
    if (wid >= Mn) return;
    const float* xr = xc + (size_t)wid*Din;
    float v[12];
    #pragma unroll
    for (int j = 0; j < 12; ++j) v[j] = xr[lane + j*64];
    for (int e = 0; e < Rn + 2*Sn; ++e) {
        const float* wr = xw + (size_t)e*Din;
        float acc = 0.f;
        #pragma unroll
        for (int j = 0; j < 12; ++j) acc = fmaf(v[j], wr[lane + j*64], acc);
        #pragma unroll
        for (int off = 32; off; off >>= 1) acc += __shfl_xor(acc, off, 64);
        if (lane == 0) xd[(size_t)wid*40 + e] = acc;
    }
}

// ---------------------------------------------- dtproj (24->768) + softplus
__global__ __launch_bounds__(256) void k_dtproj(
    const float* __restrict__ xd, const float* __restrict__ dw,
    const float* __restrict__ db, float* __restrict__ dt)
{
    int gid = blockIdx.x*blockDim.x + threadIdx.x;
    if (gid >= Mn*Din) return;
    int d = gid % Din, m = gid / Din;
    const float* r = xd + (size_t)m*40;
    const float* w = dw + (size_t)d*Rn;
    float acc = db[d];
    #pragma unroll
    for (int k = 0; k < Rn; ++k) acc = fmaf(r[k], w[k], acc);
    dt[gid] = (acc > 20.f) ? acc : log1pf(__expf(acc));
}

// ---------------- chunked scan phase A: per-chunk summary (Sdt, H[8])
// thread -> (b,c,d): gid = (b*NC + c)*Din + d
__global__ __launch_bounds__(256) void scanA(
    const float* __restrict__ u, const float* __restrict__ dt,
    const float* __restrict__ xd, const float* __restrict__ A_log,
    float* __restrict__ Hsum, float* __restrict__ dtsum)
{
    int gid = blockIdx.x*blockDim.x + threadIdx.x;
    if (gid >= Bn*NC*Din) return;
    int d = gid % Din;
    int bc = gid / Din;
    int c = bc % NC, b = bc / NC;
    float A[Sn];
    #pragma unroll
    for (int s = 0; s < Sn; ++s) A[s] = -__expf(A_log[d*Sn + s]);
    float hs[Sn] = {0,0,0,0,0,0,0,0};
    float sdt = 0.f;
    int l0 = c*CL;
    const float* up  = u  + ((size_t)b*Ln + l0)*Din + d;
    const float* dtp = dt + ((size_t)b*Ln + l0)*Din + d;
    const float* xp  = xd + ((size_t)b*Ln + l0)*40;
    #pragma unroll 7
    for (int l = 0; l < CL; ++l) {
        float dtv = dtp[(size_t)l*Din];
        float uv  = up [(size_t)l*Din];
        const float4* xr4 = (const float4*)(xp + l*40 + Rn);
        float4 Bv0 = xr4[0], Bv1 = xr4[1];
        float du = dtv * uv;
        sdt += dtv;
        hs[0] = fmaf(__expf(dtv*A[0]), hs[0], du*Bv0.x);
        hs[1] = fmaf(__expf(dtv*A[1]), hs[1], du*Bv0.y);
        hs[2] = fmaf(__expf(dtv*A[2]), hs[2], du*Bv0.z);
        hs[3] = fmaf(__expf(dtv*A[3]), hs[3], du*Bv0.w);
        hs[4] = fmaf(__expf(dtv*A[4]), hs[4], du*Bv1.x);
        hs[5] = fmaf(__expf(dtv*A[5]), hs[5], du*Bv1.y);
        hs[6] = fmaf(__expf(dtv*A[6]), hs[6], du*Bv1.z);
        hs[7] = fmaf(__expf(dtv*A[7]), hs[7], du*Bv1.w);
    }
    float4* Hp = (float4*)(Hsum + (size_t)gid*8);
    Hp[0] = make_float4(hs[0], hs[1], hs[2], hs[3]);
    Hp[1] = make_float4(hs[4], hs[5], hs[6], hs[7]);
    dtsum[gid] = sdt;
}

// ---------------- chunked scan phase B: serial fixup over NC chunks
// thread -> (b,d); writes h_in for each chunk
__global__ __launch_bounds__(256) void scanB(
    const float* __restrict__ A_log, const float* __restrict__ Hsum,
    const float* __restrict__ dtsum, float* __restrict__ hin)
{
    int gid = blockIdx.x*blockDim.x + threadIdx.x;
    if (gid >= Bn*Din) return;
    int d = gid % Din, b = gid / Din;
    float A[Sn];
    #pragma unroll
    for (int s = 0; s < Sn; ++s) A[s] = -__expf(A_log[d*Sn + s]);
    float h[Sn] = {0,0,0,0,0,0,0,0};
    #pragma unroll
    for (int c = 0; c < NC; ++c) {
        size_t idx = (size_t)(b*NC + c)*Din + d;
        float4* hp = (float4*)(hin + idx*8);
        hp[0] = make_float4(h[0], h[1], h[2], h[3]);
        hp[1] = make_float4(h[4], h[5], h[6], h[7]);
        float sdt = dtsum[idx];
        const float4* Hp = (const float4*)(Hsum + idx*8);
        float4 H0 = Hp[0], H1 = Hp[1];
        h[0] = fmaf(__expf(A[0]*sdt), h[0], H0.x);
        h[1] = fmaf(__expf(A[1]*sdt), h[1], H0.y);
        h[2] = fmaf(__expf(A[2]*sdt), h[2], H0.z);
        h[3] = fmaf(__expf(A[3]*sdt), h[3], H0.w);
        h[4] = fmaf(__expf(A[4]*sdt), h[4], H1.x);
        h[5] = fmaf(__expf(A[5]*sdt), h[5], H1.y);
        h[6] = fmaf(__expf(A[6]*sdt), h[6], H1.z);
        h[7] = fmaf(__expf(A[7]*sdt), h[7], H1.w);
    }
}

// ---------------- chunked scan phase C: final local scan + y emit
__global__ __launch_bounds__(256) void scanC(
    const float* __restrict__ u, const float* __restrict__ dt,
    const float* __restrict__ xd, const float* __restrict__ A_log,
    const float* __restrict__ Dp, const float* __restrict__ hin,
    float* __restrict__ y, int reverse, int accum)
{
    int gid = blockIdx.x*blockDim.x + threadIdx.x;
    if (gid >= Bn*NC*Din) return;
    int d = gid % Din;
    int bc = gid / Din;
    int c = bc % NC, b = bc / NC;
    float A[Sn];
    #pragma unroll
    for (int s = 0; s < Sn; ++s) A[s] = -__expf(A_log[d*Sn + s]);
    const float4* hp = (const float4*)(hin + (size_t)gid*8);
    float4 h0 = hp[0], h1 = hp[1];
    float hs[Sn] = {h0.x, h0.y, h0.z, h0.w, h1.x, h1.y, h1.z, h1.w};
    float Dd = Dp[d];
    int l0 = c*CL;
    const float* up  = u  + ((size_t)b*Ln + l0)*Din + d;
    const float* dtp = dt + ((size_t)b*Ln + l0)*Din + d;
    const float* xp  = xd + ((size_t)b*Ln + l0)*40;
    float* yp = y + (size_t)b*Ln*Din + d;
    #pragma unroll 7
    for (int l = 0; l < CL; ++l) {
        float dtv = dtp[(size_t)l*Din];
        float uv  = up [(size_t)l*Din];
        const float4* xr4 = (const float4*)(xp + l*40 + Rn);
        float4 Bv0 = xr4[0], Bv1 = xr4[1], Cv0 = xr4[2], Cv1 = xr4[3];
        float du = dtv * uv;
        float yv = 0.f;
        hs[0] = fmaf(__expf(dtv*A[0]), hs[0], du*Bv0.x); yv = fmaf(hs[0], Cv0.x, yv);
        hs[1] = fmaf(__expf(dtv*A[1]), hs[1], du*Bv0.y); yv = fmaf(hs[1], Cv0.y, yv);
        hs[2] = fmaf(__expf(dtv*A[2]), hs[2], du*Bv0.z); yv = fmaf(hs[2], Cv0.z, yv);
        hs[3] = fmaf(__expf(dtv*A[3]), hs[3], du*Bv0.w); yv = fmaf(hs[3], Cv0.w, yv);
        hs[4] = fmaf(__expf(dtv*A[4]), hs[4], du*Bv1.x); yv = fmaf(hs[4], Cv1.x, yv);
        hs[5] = fmaf(__expf(dtv*A[5]), hs[5], du*Bv1.y); yv = fmaf(hs[5], Cv1.y, yv);
        hs[6] = fmaf(__expf(dtv*A[6]), hs[6], du*Bv1.z); yv = fmaf(hs[6], Cv1.z, yv);
        hs[7] = fmaf(__expf(dtv*A[7]), hs[7], du*Bv1.w); yv = fmaf(hs[7], Cv1.w, yv);
        yv = fmaf(uv, Dd, yv);
        int gl = l0 + l;
        int ol = reverse ? (Ln - 1 - gl) : gl;
        float* dst = yp + (size_t)ol*Din;
        if (accum) *dst += yv; else *dst = yv;
    }
}

// ------------------------------------------------------------- final rmsnorm
__global__ __launch_bounds__(256) void final_k(
    const float* __restrict__ h, const float* __restrict__ res,
    const float* __restrict__ w, float* __restrict__ out)
{
    int wid  = (blockIdx.x * blockDim.x + threadIdx.x) >> 6;
    int lane = threadIdx.x & 63;
    if (wid >= Mn) return;
    const float* hp = h + (size_t)wid*En;
    const float* rp = res + (size_t)wid*En;
    float v[6]; float ss = 0.f;
    #pragma unroll
    for (int j = 0; j < 6; ++j) {
        int e = lane + j*64;
        float r = hp[e] + rp[e];
        v[j] = r; ss = fmaf(r, r, ss);
    }
    #pragma unroll
    for (int off = 32; off; off >>= 1) ss += __shfl_xor(ss, off, 64);
    float scale = rsqrtf(ss * (1.f/(float)En) + 1e-5f);
    #pragma unroll
    for (int j = 0; j < 6; ++j) {
        int e = lane + j*64;
        out[(size_t)wid*En + e] = v[j] * scale * w[e];
    }
}

extern "C" void kernel_launch(void* const* d_in, const int* in_sizes, int n_in,
                              void* d_out, int out_size, void* d_ws, size_t ws_size,
                              hipStream_t stream)
{
    const float* x         = (const float*)d_in[0];
    const float* patch_w   = (const float*)d_in[1];
    const float* patch_b   = (const float*)d_in[2];
    const float* pos_embed = (const float*)d_in[3];
    const float* in_proj_w = (const float*)d_in[4];
    const float* conv_w    = (const float*)d_in[5];
    const float* conv_b    = (const float*)d_in[6];
    const float* xproj_w   = (const float*)d_in[7];
    const float* dtproj_w  = (const float*)d_in[8];
    const float* dtproj_b  = (const float*)d_in[9];
    const float* A_log     = (const float*)d_in[10];
    const float* D_param   = (const float*)d_in[11];
    const float* outproj_w = (const float*)d_in[12];
    const float* norm_w    = (const float*)d_in[13];
    const float* conv_wb   = (const float*)d_in[14];
    const float* conv_bb   = (const float*)d_in[15];
    const float* xproj_wb  = (const float*)d_in[16];
    const float* dtproj_wb = (const float*)d_in[17];
    const float* dtproj_bb = (const float*)d_in[18];
    const float* A_log_b   = (const float*)d_in[19];
    const float* D_b       = (const float*)d_in[20];
    const float* norm_f_w  = (const float*)d_in[21];

    // flat fp32 carve: ~31.7 MB (ws >= 41.5 MB per r1-era evidence)
    float* p    = (float*)d_ws;
    float* h    = p;  p += (size_t)Mn*En;
    float* res  = p;  p += (size_t)Mn*En;
    float* hn   = p;  p += (size_t)Mn*En;
    float* xz   = p;  p += (size_t)Mn*1536;
    float* xc   = p;  p += (size_t)Mn*Din;
    float* xd   = p;  p += (size_t)Mn*40;
    float* dt   = p;  p += (size_t)Mn*Din;
    float* yt   = p;  p += (size_t)Mn*Din;
    float* Hsum = p;  p += (size_t)Bn*NC*Din*Sn;   // 196608
    float* dtsm = p;  p += (size_t)Bn*NC*Din;      // 24576
    float* hin  = p;  p += (size_t)Bn*NC*Din*Sn;   // 196608
    size_t needed = (size_t)(p - (float*)d_ws) * sizeof(float);
    if (ws_size < needed) return;

    const int wave_blocks = (Mn*64)/256;             // 392
    const int B_md   = (Mn*Din + 255)/256;           // 4704
    const int B_bd   = (Bn*Din + 255)/256;           // 6
    const int B_bcd  = (Bn*NC*Din + 255)/256;        // 96
    const int mTiles = (Mn + 63)/64;                 // 25 (ceil)

    patch_embed<<<Mn, 256, 0, stream>>>(x, patch_w, patch_b, pos_embed, h);

    for (int i = 0; i < DEPTH; ++i) {
        rms_residual<<<wave_blocks, 256, 0, stream>>>(h, res, hn, norm_w + (size_t)i*En, i == 0);

        dim3 g1(1536/64, mTiles);
        gemm64<0><<<g1, 256, 0, stream>>>(hn, En, in_proj_w + (size_t)i*1536*En,
                                          nullptr, 0, xz, 1536, Mn, 1536, En);

        const float* Al = A_log + (size_t)i*Din*Sn;
        k_conv<<<B_md, 256, 0, stream>>>(xz, conv_w + (size_t)i*Din*4,
                                         conv_b + (size_t)i*Din, xc, 0);
        xproj_k<<<wave_blocks, 256, 0, stream>>>(xc, xproj_w + (size_t)i*40*Din, xd);
        k_dtproj<<<B_md, 256, 0, stream>>>(xd, dtproj_w + (size_t)i*Din*Rn,
                                           dtproj_b + (size_t)i*Din, dt);
        scanA<<<B_bcd, 256, 0, stream>>>(xc, dt, xd, Al, Hsum, dtsm);
        scanB<<<B_bd, 256, 0, stream>>>(Al, Hsum, dtsm, hin);
        scanC<<<B_bcd, 256, 0, stream>>>(xc, dt, xd, Al, D_param + (size_t)i*Din,
                                         hin, yt, 0, 0);

        if (i < NSPA) {
            const float* Alb = A_log_b + (size_t)i*Din*Sn;
            k_conv<<<B_md, 256, 0, stream>>>(xz, conv_wb + (size_t)i*Din*4,
                                             conv_bb + (size_t)i*Din, xc, 1);
            xproj_k<<<wave_blocks, 256, 0, stream>>>(xc, xproj_wb + (size_t)i*40*Din, xd);
            k_dtproj<<<B_md, 256, 0, stream>>>(xd, dtproj_wb + (size_t)i*Din*Rn,
                                               dtproj_bb + (size_t)i*Din, dt);
            scanA<<<B_bcd, 256, 0, stream>>>(xc, dt, xd, Alb, Hsum, dtsm);
            scanB<<<B_bd, 256, 0, stream>>>(Alb, Hsum, dtsm, hin);
            scanC<<<B_bcd, 256, 0, stream>>>(xc, dt, xd, Alb, D_b + (size_t)i*Din,
                                             hin, yt, 1, 1);
        }

        dim3 g2(En/64, mTiles);
        gemm64<1><<<g2, 256, 0, stream>>>(yt, Din, outproj_w + (size_t)i*En*Din,
                                          xz + Din, 1536, h, En, Mn, En, Din);
    }

    final_k<<<wave_blocks, 256, 0, stream>>>(h, res, norm_f_w, (float*)d_out);
}

// Round 11
// 3081.074 us; speedup vs baseline: 8.7343x; 1.0800x over previous
//
#include <hip/hip_runtime.h>
#include <hip/hip_bf16.h>
#include <math.h>

// EndoMamba r11: patch-embed as GEMM; conv+dtproj fused into xproj/scan
// (r3/r4-validated patterns); NC=56 chunked scan. Inputs fp32, output fp32.
#define Bn   2
#define Tn   4
#define Nn   196
#define Ln   784
#define Mn   1568
#define En   384
#define Din  768
#define Sn   8
#define Rn   24
#define DEPTH 12
#define NSPA 6
#define NC   56
#define CL   14     // 784 = 56*14

__device__ __forceinline__ float siluf(float v) { return v / (1.f + __expf(-v)); }

// ------------------------------------------- patch gather: pm[m,768] (coalesced)
__global__ __launch_bounds__(256) void k_patch(
    const float* __restrict__ x, float* __restrict__ pm)
{
    int gid = blockIdx.x*blockDim.x + threadIdx.x;
    if (gid >= Mn*768) return;
    int idx = gid % 768, token = gid / 768;
    int b = token / Ln, l = token % Ln;
    int t = l / Nn, n = l % Nn;
    int hh = n / 14, ww = n % 14;
    int c = idx >> 8, rem = idx & 255, p = rem >> 4, q = rem & 15;
    pm[gid] = x[(((size_t)(b*3 + c)*Tn + t)*224 + (hh*16 + p))*224 + (ww*16 + q)];
}

// ------------------------------------- embed epilogue: h += pb + pos + pe
__global__ __launch_bounds__(256) void k_posadd(
    float* __restrict__ h, const float* __restrict__ pb,
    const float* __restrict__ pos)
{
    int gid = blockIdx.x*blockDim.x + threadIdx.x;
    if (gid >= Mn*En) return;
    int e = gid % En, token = gid / En;
    int l = token % Ln;
    int t = l / Nn, n = l % Nn;
    float div = __expf(-logf(10000.f) * (float)(e & ~1) / (float)En);
    float ang = (float)t * div;
    h[gid] += pb[e] + pos[n*En + e] + ((e & 1) ? cosf(ang) : sinf(ang));
}

// ------------------------------------------------------- rmsnorm (+ residual)
__global__ __launch_bounds__(256) void rms_residual(
    const float* __restrict__ hin, float* __restrict__ res,
    float* __restrict__ hn, const float* __restrict__ w, int first)
{
    int wid  = (blockIdx.x * blockDim.x + threadIdx.x) >> 6;   // token
    int lane = threadIdx.x & 63;
    if (wid >= Mn) return;
    const float* hp = hin + (size_t)wid*En;
    float* rp = res + (size_t)wid*En;
    float v[6]; float ss = 0.f;
    #pragma unroll
    for (int j = 0; j < 6; ++j) {
        int e = lane + j*64;
        float r = first ? hp[e] : (hp[e] + rp[e]);
        v[j] = r; ss = fmaf(r, r, ss);
    }
    #pragma unroll
    for (int off = 32; off; off >>= 1) ss += __shfl_xor(ss, off, 64);
    float scale = rsqrtf(ss * (1.f/(float)En) + 1e-5f);
    #pragma unroll
    for (int j = 0; j < 6; ++j) {
        int e = lane + j*64;
        rp[e] = v[j];
        hn[(size_t)wid*En + e] = v[j] * scale * w[e];
    }
}

// --------------------------------------------------- fp32 tiled GEMM C=A*W^T
template<int GATE>
__global__ __launch_bounds__(256) void gemm64(
    const float* __restrict__ A, int lda,
    const float* __restrict__ W,
    const float* __restrict__ Z, int ldz,
    float* __restrict__ C, int ldc,
    int M, int N, int K)
{
    __shared__ float As[16][64];
    __shared__ float Bs[16][64];
    int n0 = blockIdx.x * 64;
    int m0 = blockIdx.y * 64;
    int tid = threadIdx.x;
    int tx = tid & 15, ty = tid >> 4;
    int lrow = tid >> 2;            // 0..63
    int lk   = (tid & 3) << 2;      // 0,4,8,12
    float acc[4][4] = {};
    for (int k0 = 0; k0 < K; k0 += 16) {
        int mg = m0 + lrow; if (mg >= M) mg = M - 1;   // clamp: partial m-tile
        float4 av = *(const float4*)(A + (size_t)mg*lda + (k0 + lk));
        if (GATE) {
            float4 zv = *(const float4*)(Z + (size_t)mg*ldz + (k0 + lk));
            av.x *= siluf(zv.x);
            av.y *= siluf(zv.y);
            av.z *= siluf(zv.z);
            av.w *= siluf(zv.w);
        }
        float4 wv = *(const float4*)(W + (size_t)(n0 + lrow)*K + (k0 + lk));
        __syncthreads();
        As[lk+0][lrow]=av.x; As[lk+1][lrow]=av.y; As[lk+2][lrow]=av.z; As[lk+3][lrow]=av.w;
        Bs[lk+0][lrow]=wv.x; Bs[lk+1][lrow]=wv.y; Bs[lk+2][lrow]=wv.z; Bs[lk+3][lrow]=wv.w;
        __syncthreads();
        #pragma unroll
        for (int kk = 0; kk < 16; ++kk) {
            float4 a = *(const float4*)&As[kk][ty<<2];
            float4 b = *(const float4*)&Bs[kk][tx<<2];
            acc[0][0]=fmaf(a.x,b.x,acc[0][0]); acc[0][1]=fmaf(a.x,b.y,acc[0][1]);
            acc[0][2]=fmaf(a.x,b.z,acc[0][2]); acc[0][3]=fmaf(a.x,b.w,acc[0][3]);
            acc[1][0]=fmaf(a.y,b.x,acc[1][0]); acc[1][1]=fmaf(a.y,b.y,acc[1][1]);
            acc[1][2]=fmaf(a.y,b.z,acc[1][2]); acc[1][3]=fmaf(a.y,b.w,acc[1][3]);
            acc[2][0]=fmaf(a.z,b.x,acc[2][0]); acc[2][1]=fmaf(a.z,b.y,acc[2][1]);
            acc[2][2]=fmaf(a.z,b.z,acc[2][2]); acc[2][3]=fmaf(a.z,b.w,acc[2][3]);
            acc[3][0]=fmaf(a.w,b.x,acc[3][0]); acc[3][1]=fmaf(a.w,b.y,acc[3][1]);
            acc[3][2]=fmaf(a.w,b.z,acc[3][2]); acc[3][3]=fmaf(a.w,b.w,acc[3][3]);
        }
    }
    #pragma unroll
    for (int i = 0; i < 4; ++i) {
        int mg = m0 + (ty<<2) + i;
        if (mg < M) {
            float* cp = C + (size_t)mg*ldc + n0 + (tx<<2);
            cp[0]=acc[i][0]; cp[1]=acc[i][1]; cp[2]=acc[i][2]; cp[3]=acc[i][3];
        }
    }
}

// ---------------- fused conv+silu+xproj (768->40), wave per token [r3/r4-validated]
__global__ __launch_bounds__(256) void xprojc_k(
    const float* __restrict__ xz, const float* __restrict__ cw,
    const float* __restrict__ cb, const float* __restrict__ xw,
    float* __restrict__ xd, int reverse)
{
    int wid  = (blockIdx.x*blockDim.x + threadIdx.x) >> 6;    // m (processed order)
    int lane = threadIdx.x & 63;
    if (wid >= Mn) return;
    int b = wid / Ln, l = wid % Ln;
    float u[12];
    #pragma unroll
    for (int j = 0; j < 12; ++j) {
        int d = lane + j*64;
        float4 cwv = *(const float4*)(cw + d*4);
        float acc = cb[d];
        #pragma unroll
        for (int k = 0; k < 4; ++k) {
            int ls = l - 3 + k;
            if (ls < 0) continue;
            int lsrc = reverse ? (Ln - 1 - ls) : ls;
            float cwk = (k==0)?cwv.x:(k==1)?cwv.y:(k==2)?cwv.z:cwv.w;
            acc = fmaf(xz[(size_t)(b*Ln + lsrc)*1536 + d], cwk, acc);
        }
        u[j] = siluf(acc);
    }
    for (int e = 0; e < Rn + 2*Sn; ++e) {
        const float* wr = xw + (size_t)e*Din;
        float acc = 0.f;
        #pragma unroll
        for (int j = 0; j < 12; ++j) acc = fmaf(u[j], wr[lane + j*64], acc);
        #pragma unroll
        for (int off = 32; off; off >>= 1) acc += __shfl_xor(acc, off, 64);
        if (lane == 0) xd[(size_t)wid*40 + e] = acc;
    }
}

// ---------------- scan phase A: per-chunk (Sdt, H[8]); conv+dt inline
__global__ __launch_bounds__(256) void scanA(
    const float* __restrict__ xz, const float* __restrict__ cw,
    const float* __restrict__ cb, const float* __restrict__ xd,
    const float* __restrict__ dw, const float* __restrict__ db,
    const float* __restrict__ A_log,
    float* __restrict__ Hsum, float* __restrict__ dtsum, int reverse)
{
    int gid = blockIdx.x*blockDim.x + threadIdx.x;
    if (gid >= Bn*NC*Din) return;
    int d = gid % Din;
    int bc = gid / Din;
    int c = bc % NC, b = bc / NC;
    float A[Sn];
    #pragma unroll
    for (int s = 0; s < Sn; ++s) A[s] = -__expf(A_log[d*Sn + s]);
    float4 cwv = *(const float4*)(cw + d*4);
    float cbv = cb[d];
    float dwr[Rn];
    #pragma unroll
    for (int r = 0; r < Rn; ++r) dwr[r] = dw[d*Rn + r];
    float dbv = db[d];
    float hs[Sn] = {0,0,0,0,0,0,0,0};
    float sdt = 0.f;
    int l0 = c*CL;
    #pragma unroll
    for (int l = 0; l < CL; ++l) {
        int gl = l0 + l;
        float acc = cbv;
        #pragma unroll
        for (int k = 0; k < 4; ++k) {
            int ls = gl - 3 + k;
            if (ls < 0) continue;
            int lsrc = reverse ? (Ln - 1 - ls) : ls;
            float cwk = (k==0)?cwv.x:(k==1)?cwv.y:(k==2)?cwv.z:cwv.w;
            acc = fmaf(xz[(size_t)(b*Ln + lsrc)*1536 + d], cwk, acc);
        }
        float uv = siluf(acc);
        const float* xr = xd + (size_t)(b*Ln + gl)*40;
        float dta = dbv;
        #pragma unroll
        for (int r = 0; r < Rn; ++r) dta = fmaf(xr[r], dwr[r], dta);
        float dtv = (dta > 20.f) ? dta : log1pf(__expf(dta));
        sdt += dtv;
        const float4* B4 = (const float4*)(xr + Rn);
        float4 Bv0 = B4[0], Bv1 = B4[1];
        float du = dtv * uv;
        hs[0] = fmaf(__expf(dtv*A[0]), hs[0], du*Bv0.x);
        hs[1] = fmaf(__expf(dtv*A[1]), hs[1], du*Bv0.y);
        hs[2] = fmaf(__expf(dtv*A[2]), hs[2], du*Bv0.z);
        hs[3] = fmaf(__expf(dtv*A[3]), hs[3], du*Bv0.w);
        hs[4] = fmaf(__expf(dtv*A[4]), hs[4], du*Bv1.x);
        hs[5] = fmaf(__expf(dtv*A[5]), hs[5], du*Bv1.y);
        hs[6] = fmaf(__expf(dtv*A[6]), hs[6], du*Bv1.z);
        hs[7] = fmaf(__expf(dtv*A[7]), hs[7], du*Bv1.w);
    }
    float4* Hp = (float4*)(Hsum + (size_t)gid*8);
    Hp[0] = make_float4(hs[0], hs[1], hs[2], hs[3]);
    Hp[1] = make_float4(hs[4], hs[5], hs[6], hs[7]);
    dtsum[gid] = sdt;
}

// ---------------- scan phase B: serial fixup over NC chunks, thread/(b,d)
__global__ __launch_bounds__(256) void scanB(
    const float* __restrict__ A_log, const float* __restrict__ Hsum,
    const float* __restrict__ dtsum, float* __restrict__ hin)
{
    int gid = blockIdx.x*blockDim.x + threadIdx.x;
    if (gid >= Bn*Din) return;
    int d = gid % Din, b = gid / Din;
    float A[Sn];
    #pragma unroll
    for (int s = 0; s < Sn; ++s) A[s] = -__expf(A_log[d*Sn + s]);
    float h[Sn] = {0,0,0,0,0,0,0,0};
    #pragma unroll 8
    for (int c = 0; c < NC; ++c) {
        size_t idx = (size_t)(b*NC + c)*Din + d;
        float4* hp = (float4*)(hin + idx*8);
        hp[0] = make_float4(h[0], h[1], h[2], h[3]);
        hp[1] = make_float4(h[4], h[5], h[6], h[7]);
        float sdt = dtsum[idx];
        const float4* Hp = (const float4*)(Hsum + idx*8);
        float4 H0 = Hp[0], H1 = Hp[1];
        h[0] = fmaf(__expf(A[0]*sdt), h[0], H0.x);
        h[1] = fmaf(__expf(A[1]*sdt), h[1], H0.y);
        h[2] = fmaf(__expf(A[2]*sdt), h[2], H0.z);
        h[3] = fmaf(__expf(A[3]*sdt), h[3], H0.w);
        h[4] = fmaf(__expf(A[4]*sdt), h[4], H1.x);
        h[5] = fmaf(__expf(A[5]*sdt), h[5], H1.y);
        h[6] = fmaf(__expf(A[6]*sdt), h[6], H1.z);
        h[7] = fmaf(__expf(A[7]*sdt), h[7], H1.w);
    }
}

// ---------------- scan phase C: seeded local scan + y emit; conv+dt inline
__global__ __launch_bounds__(256) void scanC(
    const float* __restrict__ xz, const float* __restrict__ cw,
    const float* __restrict__ cb, const float* __restrict__ xd,
    const float* __restrict__ dw, const float* __restrict__ db,
    const float* __restrict__ A_log, const float* __restrict__ Dp,
    const float* __restrict__ hin, float* __restrict__ y,
    int reverse, int accum)
{
    int gid = blockIdx.x*blockDim.x + threadIdx.x;
    if (gid >= Bn*NC*Din) return;
    int d = gid % Din;
    int bc = gid / Din;
    int c = bc % NC, b = bc / NC;
    float A[Sn];
    #pragma unroll
    for (int s = 0; s < Sn; ++s) A[s] = -__expf(A_log[d*Sn + s]);
    float4 cwv = *(const float4*)(cw + d*4);
    float cbv = cb[d];
    float dwr[Rn];
    #pragma unroll
    for (int r = 0; r < Rn; ++r) dwr[r] = dw[d*Rn + r];
    float dbv = db[d];
    const float4* hp = (const float4*)(hin + (size_t)gid*8);
    float4 h0 = hp[0], h1 = hp[1];
    float hs[Sn] = {h0.x, h0.y, h0.z, h0.w, h1.x, h1.y, h1.z, h1.w};
    float Dd = Dp[d];
    int l0 = c*CL;
    float* yp = y + (size_t)b*Ln*Din + d;
    #pragma unroll
    for (int l = 0; l < CL; ++l) {
        int gl = l0 + l;
        float acc = cbv;
        #pragma unroll
        for (int k = 0; k < 4; ++k) {
            int ls = gl - 3 + k;
            if (ls < 0) continue;
            int lsrc = reverse ? (Ln - 1 - ls) : ls;
            float cwk = (k==0)?cwv.x:(k==1)?cwv.y:(k==2)?cwv.z:cwv.w;
            acc = fmaf(xz[(size_t)(b*Ln + lsrc)*1536 + d], cwk, acc);
        }
        float uv = siluf(acc);
        const float* xr = xd + (size_t)(b*Ln + gl)*40;
        float dta = dbv;
        #pragma unroll
        for (int r = 0; r < Rn; ++r) dta = fmaf(xr[r], dwr[r], dta);
        float dtv = (dta > 20.f) ? dta : log1pf(__expf(dta));
        const float4* B4 = (const float4*)(xr + Rn);
        float4 Bv0 = B4[0], Bv1 = B4[1], Cv0 = B4[2], Cv1 = B4[3];
        float du = dtv * uv;
        float yv = 0.f;
        hs[0] = fmaf(__expf(dtv*A[0]), hs[0], du*Bv0.x); yv = fmaf(hs[0], Cv0.x, yv);
        hs[1] = fmaf(__expf(dtv*A[1]), hs[1], du*Bv0.y); yv = fmaf(hs[1], Cv0.y, yv);
        hs[2] = fmaf(__expf(dtv*A[2]), hs[2], du*Bv0.z); yv = fmaf(hs[2], Cv0.z, yv);
        hs[3] = fmaf(__expf(dtv*A[3]), hs[3], du*Bv0.w); yv = fmaf(hs[3], Cv0.w, yv);
        hs[4] = fmaf(__expf(dtv*A[4]), hs[4], du*Bv1.x); yv = fmaf(hs[4], Cv1.x, yv);
        hs[5] = fmaf(__expf(dtv*A[5]), hs[5], du*Bv1.y); yv = fmaf(hs[5], Cv1.y, yv);
        hs[6] = fmaf(__expf(dtv*A[6]), hs[6], du*Bv1.z); yv = fmaf(hs[6], Cv1.z, yv);
        hs[7] = fmaf(__expf(dtv*A[7]), hs[7], du*Bv1.w); yv = fmaf(hs[7], Cv1.w, yv);
        yv = fmaf(uv, Dd, yv);
        int ol = reverse ? (Ln - 1 - gl) : gl;
        float* dst = yp + (size_t)ol*Din;
        if (accum) *dst += yv; else *dst = yv;
    }
}

// ------------------------------------------------------------- final rmsnorm
__global__ __launch_bounds__(256) void final_k(
    const float* __restrict__ h, const float* __restrict__ res,
    const float* __restrict__ w, float* __restrict__ out)
{
    int wid  = (blockIdx.x * blockDim.x + threadIdx.x) >> 6;
    int lane = threadIdx.x & 63;
    if (wid >= Mn) return;
    const float* hp = h + (size_t)wid*En;
    const float* rp = res + (size_t)wid*En;
    float v[6]; float ss = 0.f;
    #pragma unroll
    for (int j = 0; j < 6; ++j) {
        int e = lane + j*64;
        float r = hp[e] + rp[e];
        v[j] = r; ss = fmaf(r, r, ss);
    }
    #pragma unroll
    for (int off = 32; off; off >>= 1) ss += __shfl_xor(ss, off, 64);
    float scale = rsqrtf(ss * (1.f/(float)En) + 1e-5f);
    #pragma unroll
    for (int j = 0; j < 6; ++j) {
        int e = lane + j*64;
        out[(size_t)wid*En + e] = v[j] * scale * w[e];
    }
}

extern "C" void kernel_launch(void* const* d_in, const int* in_sizes, int n_in,
                              void* d_out, int out_size, void* d_ws, size_t ws_size,
                              hipStream_t stream)
{
    const float* x         = (const float*)d_in[0];
    const float* patch_w   = (const float*)d_in[1];
    const float* patch_b   = (const float*)d_in[2];
    const float* pos_embed = (const float*)d_in[3];
    const float* in_proj_w = (const float*)d_in[4];
    const float* conv_w    = (const float*)d_in[5];
    const float* conv_b    = (const float*)d_in[6];
    const float* xproj_w   = (const float*)d_in[7];
    const float* dtproj_w  = (const float*)d_in[8];
    const float* dtproj_b  = (const float*)d_in[9];
    const float* A_log     = (const float*)d_in[10];
    const float* D_param   = (const float*)d_in[11];
    const float* outproj_w = (const float*)d_in[12];
    const float* norm_w    = (const float*)d_in[13];
    const float* conv_wb   = (const float*)d_in[14];
    const float* conv_bb   = (const float*)d_in[15];
    const float* xproj_wb  = (const float*)d_in[16];
    const float* dtproj_wb = (const float*)d_in[17];
    const float* dtproj_bb = (const float*)d_in[18];
    const float* A_log_b   = (const float*)d_in[19];
    const float* D_b       = (const float*)d_in[20];
    const float* norm_f_w  = (const float*)d_in[21];

    // fp32 carve ~33 MB (ws >= 41.5 MB per r1-era evidence)
    float* p    = (float*)d_ws;
    float* h    = p;  p += (size_t)Mn*En;
    float* res  = p;  p += (size_t)Mn*En;
    float* hn   = p;  p += (size_t)Mn*En;
    float* xz   = p;  p += (size_t)Mn*1536;
    float* pm   = p;  p += (size_t)Mn*768;         // patch matrix (embed only)
    float* xd   = p;  p += (size_t)Mn*40;
    float* yt   = p;  p += (size_t)Mn*Din;
    float* Hsum = p;  p += (size_t)Bn*NC*Din*Sn;   // 688128
    float* dtsm = p;  p += (size_t)Bn*NC*Din;      // 86016
    float* hin  = p;  p += (size_t)Bn*NC*Din*Sn;   // 688128
    size_t needed = (size_t)(p - (float*)d_ws) * sizeof(float);
    if (ws_size < needed) return;

    const int wave_blocks = (Mn*64)/256;             // 392
    const int B_me   = (Mn*En + 255)/256;            // 2352
    const int B_md   = (Mn*768 + 255)/256;           // 4704
    const int B_bd   = (Bn*Din + 255)/256;           // 6
    const int B_bcd  = (Bn*NC*Din + 255)/256;        // 336
    const int mTiles = (Mn + 63)/64;                 // 25 (ceil)

    // ---- patch embed as GEMM: gather -> gemm64 -> pos/pe epilogue
    k_patch<<<B_md, 256, 0, stream>>>(x, pm);
    dim3 g0(En/64, mTiles);
    gemm64<0><<<g0, 256, 0, stream>>>(pm, 768, patch_w, nullptr, 0, h, En, Mn, En, 768);
    k_posadd<<<B_me, 256, 0, stream>>>(h, patch_b, pos_embed);

    for (int i = 0; i < DEPTH; ++i) {
        rms_residual<<<wave_blocks, 256, 0, stream>>>(h, res, hn, norm_w + (size_t)i*En, i == 0);

        dim3 g1(1536/64, mTiles);
        gemm64<0><<<g1, 256, 0, stream>>>(hn, En, in_proj_w + (size_t)i*1536*En,
                                          nullptr, 0, xz, 1536, Mn, 1536, En);

        const float* cwf = conv_w + (size_t)i*Din*4;
        const float* cbf = conv_b + (size_t)i*Din;
        const float* dwf = dtproj_w + (size_t)i*Din*Rn;
        const float* dbf = dtproj_b + (size_t)i*Din;
        const float* Al  = A_log + (size_t)i*Din*Sn;
        xprojc_k<<<wave_blocks, 256, 0, stream>>>(xz, cwf, cbf,
                                                  xproj_w + (size_t)i*40*Din, xd, 0);
        scanA<<<B_bcd, 256, 0, stream>>>(xz, cwf, cbf, xd, dwf, dbf, Al, Hsum, dtsm, 0);
        scanB<<<B_bd, 256, 0, stream>>>(Al, Hsum, dtsm, hin);
        scanC<<<B_bcd, 256, 0, stream>>>(xz, cwf, cbf, xd, dwf, dbf, Al,
                                         D_param + (size_t)i*Din, hin, yt, 0, 0);

        if (i < NSPA) {
            const float* cwb = conv_wb + (size_t)i*Din*4;
            const float* cbb = conv_bb + (size_t)i*Din;
            const float* dwb = dtproj_wb + (size_t)i*Din*Rn;
            const float* dbb = dtproj_bb + (size_t)i*Din;
            const float* Alb = A_log_b + (size_t)i*Din*Sn;
            xprojc_k<<<wave_blocks, 256, 0, stream>>>(xz, cwb, cbb,
                                                      xproj_wb + (size_t)i*40*Din, xd, 1);
            scanA<<<B_bcd, 256, 0, stream>>>(xz, cwb, cbb, xd, dwb, dbb, Alb, Hsum, dtsm, 1);
            scanB<<<B_bd, 256, 0, stream>>>(Alb, Hsum, dtsm, hin);
            scanC<<<B_bcd, 256, 0, stream>>>(xz, cwb, cbb, xd, dwb, dbb, Alb,
                                             D_b + (size_t)i*Din, hin, yt, 1, 1);
        }

        dim3 g2(En/64, mTiles);
        gemm64<1><<<g2, 256, 0, stream>>>(yt, Din, outproj_w + (size_t)i*En*Din,
                                          xz + Din, 1536, h, En, Mn, En, Din);
    }

    final_k<<<wave_blocks, 256, 0, stream>>>(h, res, norm_f_w, (float*)d_out);
}

// Round 12
// 2423.553 us; speedup vs baseline: 11.1040x; 1.2713x over previous
//
#include <hip/hip_runtime.h>
#include <hip/hip_bf16.h>
#include <math.h>

// EndoMamba r12: bf16 MFMA GEMMs (16x16x32), bf16 activations (hn/xz/yt/pm),
// per-launch weight cast, gate fused into scanC. fp32 residual backbone.
#define Bn   2
#define Tn   4
#define Nn   196
#define Ln   784
#define Mn   1568
#define En   384
#define Din  768
#define Sn   8
#define Rn   24
#define DEPTH 12
#define NSPA 6
#define NC   56
#define CL   14     // 784 = 56*14

typedef __attribute__((ext_vector_type(8))) short bf16x8;
typedef __attribute__((ext_vector_type(4))) float f32x4;

__device__ __forceinline__ float siluf(float v) { return v / (1.f + __expf(-v)); }
__device__ __forceinline__ float us2f(unsigned short u) {
    union { unsigned int i; float f; } v; v.i = (unsigned)u << 16; return v.f;
}
__device__ __forceinline__ unsigned short f2us(float f) {
    __hip_bfloat16 b = __float2bfloat16(f);
    return *(unsigned short*)&b;
}
__device__ __forceinline__ void cstore(float* p, float v) { *p = v; }
__device__ __forceinline__ void cstore(unsigned short* p, float v) { *p = f2us(v); }

// ------------------------------------------------ fp32 -> bf16 cast (x4)
__global__ __launch_bounds__(256) void cast4(
    const float* __restrict__ src, unsigned short* __restrict__ dst, int n4)
{
    int gid = blockIdx.x*blockDim.x + threadIdx.x;
    if (gid >= n4) return;
    float4 v = *(const float4*)(src + (size_t)gid*4);
    ushort4 o; o.x = f2us(v.x); o.y = f2us(v.y); o.z = f2us(v.z); o.w = f2us(v.w);
    *(ushort4*)(dst + (size_t)gid*4) = o;
}

// ------------------------------------------- patch gather -> pm[m,768] bf16
__global__ __launch_bounds__(256) void k_patch(
    const float* __restrict__ x, unsigned short* __restrict__ pm)
{
    int gid = blockIdx.x*blockDim.x + threadIdx.x;
    if (gid >= Mn*768) return;
    int idx = gid % 768, token = gid / 768;
    int b = token / Ln, l = token % Ln;
    int t = l / Nn, n = l % Nn;
    int hh = n / 14, ww = n % 14;
    int c = idx >> 8, rem = idx & 255, p = rem >> 4, q = rem & 15;
    pm[gid] = f2us(x[(((size_t)(b*3 + c)*Tn + t)*224 + (hh*16 + p))*224 + (ww*16 + q)]);
}

// ------------------------------------- embed epilogue: h += pb + pos + pe
__global__ __launch_bounds__(256) void k_posadd(
    float* __restrict__ h, const float* __restrict__ pb,
    const float* __restrict__ pos)
{
    int gid = blockIdx.x*blockDim.x + threadIdx.x;
    if (gid >= Mn*En) return;
    int e = gid % En, token = gid / En;
    int l = token % Ln;
    int t = l / Nn, n = l % Nn;
    float div = __expf(-logf(10000.f) * (float)(e & ~1) / (float)En);
    float ang = (float)t * div;
    h[gid] += pb[e] + pos[n*En + e] + ((e & 1) ? cosf(ang) : sinf(ang));
}

// ------------------------------------------------------- rmsnorm (+ residual)
__global__ __launch_bounds__(256) void rms_residual(
    const float* __restrict__ hin, float* __restrict__ res,
    unsigned short* __restrict__ hn, const float* __restrict__ w, int first)
{
    int wid  = (blockIdx.x * blockDim.x + threadIdx.x) >> 6;   // token
    int lane = threadIdx.x & 63;
    if (wid >= Mn) return;
    const float* hp = hin + (size_t)wid*En;
    float* rp = res + (size_t)wid*En;
    float v[6]; float ss = 0.f;
    #pragma unroll
    for (int j = 0; j < 6; ++j) {
        int e = lane + j*64;
        float r = first ? hp[e] : (hp[e] + rp[e]);
        v[j] = r; ss = fmaf(r, r, ss);
    }
    #pragma unroll
    for (int off = 32; off; off >>= 1) ss += __shfl_xor(ss, off, 64);
    float scale = rsqrtf(ss * (1.f/(float)En) + 1e-5f);
    #pragma unroll
    for (int j = 0; j < 6; ++j) {
        int e = lane + j*64;
        rp[e] = v[j];
        hn[(size_t)wid*En + e] = f2us(v[j] * scale * w[e]);
    }
}

// ------------------------- bf16 MFMA GEMM: C = A[M,K] * W[N,K]^T
// 64x64 tile, 4 waves; wave w -> m-strip w*16 x 64 n. K%32==0, N%64==0.
// Fragment layouts (m89/m91-verified): A[m=lane&15][k=quad*8+j],
// B[k=quad*8+j][n=lane&15]; C/D: m=quad*4+reg, n=lane&15.
template<typename CT>
__global__ __launch_bounds__(256) void gemm_mfma(
    const unsigned short* __restrict__ A,
    const unsigned short* __restrict__ W,
    CT* __restrict__ C, int ldc, int M, int N, int K)
{
    __shared__ unsigned short As[64][40];   // 32 k + 8 pad
    __shared__ unsigned short Bs[64][40];
    int n0 = blockIdx.x * 64;
    int m0 = blockIdx.y * 64;
    int tid = threadIdx.x;
    int wave = tid >> 6, lane = tid & 63;
    int quad = lane >> 4, fr = lane & 15;
    int arow = tid >> 2;            // 0..63
    int acol = (tid & 3) << 3;      // 0,8,16,24
    f32x4 acc[4] = {};
    for (int k0 = 0; k0 < K; k0 += 32) {
        int mg = m0 + arow; if (mg >= M) mg = M - 1;
        bf16x8 av = *(const bf16x8*)(A + (size_t)mg*K + k0 + acol);
        bf16x8 wv = *(const bf16x8*)(W + (size_t)(n0 + arow)*K + k0 + acol);
        __syncthreads();
        *(bf16x8*)&As[arow][acol] = av;
        *(bf16x8*)&Bs[arow][acol] = wv;
        __syncthreads();
        bf16x8 af = *(const bf16x8*)&As[wave*16 + fr][quad << 3];
        #pragma unroll
        for (int nt = 0; nt < 4; ++nt) {
            bf16x8 bfr = *(const bf16x8*)&Bs[nt*16 + fr][quad << 3];
            acc[nt] = __builtin_amdgcn_mfma_f32_16x16x32_bf16(af, bfr, acc[nt], 0, 0, 0);
        }
    }
    #pragma unroll
    for (int nt = 0; nt < 4; ++nt) {
        #pragma unroll
        for (int r = 0; r < 4; ++r) {
            int mg = m0 + wave*16 + quad*4 + r;
            if (mg < M) cstore(C + (size_t)mg*ldc + n0 + nt*16 + fr, acc[nt][r]);
        }
    }
}

// ---------------- fused conv+silu+xproj (768->40), wave per token
__global__ __launch_bounds__(256) void xprojc_k(
    const unsigned short* __restrict__ xz, const float* __restrict__ cw,
    const float* __restrict__ cb, const float* __restrict__ xw,
    float* __restrict__ xd, int reverse)
{
    int wid  = (blockIdx.x*blockDim.x + threadIdx.x) >> 6;
    int lane = threadIdx.x & 63;
    if (wid >= Mn) return;
    int b = wid / Ln, l = wid % Ln;
    float u[12];
    #pragma unroll
    for (int j = 0; j < 12; ++j) {
        int d = lane + j*64;
        float4 cwv = *(const float4*)(cw + d*4);
        float acc = cb[d];
        #pragma unroll
        for (int k = 0; k < 4; ++k) {
            int ls = l - 3 + k;
            if (ls < 0) continue;
            int lsrc = reverse ? (Ln - 1 - ls) : ls;
            float cwk = (k==0)?cwv.x:(k==1)?cwv.y:(k==2)?cwv.z:cwv.w;
            acc = fmaf(us2f(xz[(size_t)(b*Ln + lsrc)*1536 + d]), cwk, acc);
        }
        u[j] = siluf(acc);
    }
    for (int e = 0; e < Rn + 2*Sn; ++e) {
        const float* wr = xw + (size_t)e*Din;
        float acc = 0.f;
        #pragma unroll
        for (int j = 0; j < 12; ++j) acc = fmaf(u[j], wr[lane + j*64], acc);
        #pragma unroll
        for (int off = 32; off; off >>= 1) acc += __shfl_xor(acc, off, 64);
        if (lane == 0) xd[(size_t)wid*40 + e] = acc;
    }
}

// ---------------- scan phase A: per-chunk (Sdt, H[8]); conv+dt inline
__global__ __launch_bounds__(256) void scanA(
    const unsigned short* __restrict__ xz, const float* __restrict__ cw,
    const float* __restrict__ cb, const float* __restrict__ xd,
    const float* __restrict__ dw, const float* __restrict__ db,
    const float* __restrict__ A_log,
    float* __restrict__ Hsum, float* __restrict__ dtsum, int reverse)
{
    int gid = blockIdx.x*blockDim.x + threadIdx.x;
    if (gid >= Bn*NC*Din) return;
    int d = gid % Din;
    int bc = gid / Din;
    int c = bc % NC, b = bc / NC;
    float A[Sn];
    #pragma unroll
    for (int s = 0; s < Sn; ++s) A[s] = -__expf(A_log[d*Sn + s]);
    float4 cwv = *(const float4*)(cw + d*4);
    float cbv = cb[d];
    float dwr[Rn];
    #pragma unroll
    for (int r = 0; r < Rn; ++r) dwr[r] = dw[d*Rn + r];
    float dbv = db[d];
    float hs[Sn] = {0,0,0,0,0,0,0,0};
    float sdt = 0.f;
    int l0 = c*CL;
    #pragma unroll
    for (int l = 0; l < CL; ++l) {
        int gl = l0 + l;
        float acc = cbv;
        #pragma unroll
        for (int k = 0; k < 4; ++k) {
            int ls = gl - 3 + k;
            if (ls < 0) continue;
            int lsrc = reverse ? (Ln - 1 - ls) : ls;
            float cwk = (k==0)?cwv.x:(k==1)?cwv.y:(k==2)?cwv.z:cwv.w;
            acc = fmaf(us2f(xz[(size_t)(b*Ln + lsrc)*1536 + d]), cwk, acc);
        }
        float uv = siluf(acc);
        const float* xr = xd + (size_t)(b*Ln + gl)*40;
        float dta = dbv;
        #pragma unroll
        for (int r = 0; r < Rn; ++r) dta = fmaf(xr[r], dwr[r], dta);
        float dtv = (dta > 20.f) ? dta : log1pf(__expf(dta));
        sdt += dtv;
        const float4* B4 = (const float4*)(xr + Rn);
        float4 Bv0 = B4[0], Bv1 = B4[1];
        float du = dtv * uv;
        hs[0] = fmaf(__expf(dtv*A[0]), hs[0], du*Bv0.x);
        hs[1] = fmaf(__expf(dtv*A[1]), hs[1], du*Bv0.y);
        hs[2] = fmaf(__expf(dtv*A[2]), hs[2], du*Bv0.z);
        hs[3] = fmaf(__expf(dtv*A[3]), hs[3], du*Bv0.w);
        hs[4] = fmaf(__expf(dtv*A[4]), hs[4], du*Bv1.x);
        hs[5] = fmaf(__expf(dtv*A[5]), hs[5], du*Bv1.y);
        hs[6] = fmaf(__expf(dtv*A[6]), hs[6], du*Bv1.z);
        hs[7] = fmaf(__expf(dtv*A[7]), hs[7], du*Bv1.w);
    }
    float4* Hp = (float4*)(Hsum + (size_t)gid*8);
    Hp[0] = make_float4(hs[0], hs[1], hs[2], hs[3]);
    Hp[1] = make_float4(hs[4], hs[5], hs[6], hs[7]);
    dtsum[gid] = sdt;
}

// ---------------- scan phase B: serial fixup over NC chunks, thread/(b,d)
__global__ __launch_bounds__(256) void scanB(
    const float* __restrict__ A_log, const float* __restrict__ Hsum,
    const float* __restrict__ dtsum, float* __restrict__ hin)
{
    int gid = blockIdx.x*blockDim.x + threadIdx.x;
    if (gid >= Bn*Din) return;
    int d = gid % Din, b = gid / Din;
    float A[Sn];
    #pragma unroll
    for (int s = 0; s < Sn; ++s) A[s] = -__expf(A_log[d*Sn + s]);
    float h[Sn] = {0,0,0,0,0,0,0,0};
    #pragma unroll 8
    for (int c = 0; c < NC; ++c) {
        size_t idx = (size_t)(b*NC + c)*Din + d;
        float4* hp = (float4*)(hin + idx*8);
        hp[0] = make_float4(h[0], h[1], h[2], h[3]);
        hp[1] = make_float4(h[4], h[5], h[6], h[7]);
        float sdt = dtsum[idx];
        const float4* Hp = (const float4*)(Hsum + idx*8);
        float4 H0 = Hp[0], H1 = Hp[1];
        h[0] = fmaf(__expf(A[0]*sdt), h[0], H0.x);
        h[1] = fmaf(__expf(A[1]*sdt), h[1], H0.y);
        h[2] = fmaf(__expf(A[2]*sdt), h[2], H0.z);
        h[3] = fmaf(__expf(A[3]*sdt), h[3], H0.w);
        h[4] = fmaf(__expf(A[4]*sdt), h[4], H1.x);
        h[5] = fmaf(__expf(A[5]*sdt), h[5], H1.y);
        h[6] = fmaf(__expf(A[6]*sdt), h[6], H1.z);
        h[7] = fmaf(__expf(A[7]*sdt), h[7], H1.w);
    }
}

// -------- scan phase C: seeded local scan + y emit (+gate), conv+dt inline
// gate: yt = y * silu(z) (accum=0) or yt = (yt_raw + y) * silu(z) (accum=1)
__global__ __launch_bounds__(256) void scanC(
    const unsigned short* __restrict__ xz, const float* __restrict__ cw,
    const float* __restrict__ cb, const float* __restrict__ xd,
    const float* __restrict__ dw, const float* __restrict__ db,
    const float* __restrict__ A_log, const float* __restrict__ Dp,
    const float* __restrict__ hin, unsigned short* __restrict__ y,
    int reverse, int accum, int gate)
{
    int gid = blockIdx.x*blockDim.x + threadIdx.x;
    if (gid >= Bn*NC*Din) return;
    int d = gid % Din;
    int bc = gid / Din;
    int c = bc % NC, b = bc / NC;
    float A[Sn];
    #pragma unroll
    for (int s = 0; s < Sn; ++s) A[s] = -__expf(A_log[d*Sn + s]);
    float4 cwv = *(const float4*)(cw + d*4);
    float cbv = cb[d];
    float dwr[Rn];
    #pragma unroll
    for (int r = 0; r < Rn; ++r) dwr[r] = dw[d*Rn + r];
    float dbv = db[d];
    const float4* hp = (const float4*)(hin + (size_t)gid*8);
    float4 h0 = hp[0], h1 = hp[1];
    float hs[Sn] = {h0.x, h0.y, h0.z, h0.w, h1.x, h1.y, h1.z, h1.w};
    float Dd = Dp[d];
    int l0 = c*CL;
    unsigned short* yp = y + (size_t)b*Ln*Din + d;
    #pragma unroll
    for (int l = 0; l < CL; ++l) {
        int gl = l0 + l;
        float acc = cbv;
        #pragma unroll
        for (int k = 0; k < 4; ++k) {
            int ls = gl - 3 + k;
            if (ls < 0) continue;
            int lsrc = reverse ? (Ln - 1 - ls) : ls;
            float cwk = (k==0)?cwv.x:(k==1)?cwv.y:(k==2)?cwv.z:cwv.w;
            acc = fmaf(us2f(xz[(size_t)(b*Ln + lsrc)*1536 + d]), cwk, acc);
        }
        float uv = siluf(acc);
        const float* xr = xd + (size_t)(b*Ln + gl)*40;
        float dta = dbv;
        #pragma unroll
        for (int r = 0; r < Rn; ++r) dta = fmaf(xr[r], dwr[r], dta);
        float dtv = (dta > 20.f) ? dta : log1pf(__expf(dta));
        const float4* B4 = (const float4*)(xr + Rn);
        float4 Bv0 = B4[0], Bv1 = B4[1], Cv0 = B4[2], Cv1 = B4[3];
        float du = dtv * uv;
        float yv = 0.f;
        hs[0] = fmaf(__expf(dtv*A[0]), hs[0], du*Bv0.x); yv = fmaf(hs[0], Cv0.x, yv);
        hs[1] = fmaf(__expf(dtv*A[1]), hs[1], du*Bv0.y); yv = fmaf(hs[1], Cv0.y, yv);
        hs[2] = fmaf(__expf(dtv*A[2]), hs[2], du*Bv0.z); yv = fmaf(hs[2], Cv0.z, yv);
        hs[3] = fmaf(__expf(dtv*A[3]), hs[3], du*Bv0.w); yv = fmaf(hs[3], Cv0.w, yv);
        hs[4] = fmaf(__expf(dtv*A[4]), hs[4], du*Bv1.x); yv = fmaf(hs[4], Cv1.x, yv);
        hs[5] = fmaf(__expf(dtv*A[5]), hs[5], du*Bv1.y); yv = fmaf(hs[5], Cv1.y, yv);
        hs[6] = fmaf(__expf(dtv*A[6]), hs[6], du*Bv1.z); yv = fmaf(hs[6], Cv1.z, yv);
        hs[7] = fmaf(__expf(dtv*A[7]), hs[7], du*Bv1.w); yv = fmaf(hs[7], Cv1.w, yv);
        yv = fmaf(uv, Dd, yv);
        int ol = reverse ? (Ln - 1 - gl) : gl;
        unsigned short* dst = yp + (size_t)ol*Din;
        float val = yv;
        if (accum) val += us2f(*dst);
        if (gate) {
            float z = us2f(xz[(size_t)(b*Ln + ol)*1536 + Din + d]);
            val *= siluf(z);
        }
        *dst = f2us(val);
    }
}

// ------------------------------------------------------------- final rmsnorm
__global__ __launch_bounds__(256) void final_k(
    const float* __restrict__ h, const float* __restrict__ res,
    const float* __restrict__ w, float* __restrict__ out)
{
    int wid  = (blockIdx.x * blockDim.x + threadIdx.x) >> 6;
    int lane = threadIdx.x & 63;
    if (wid >= Mn) return;
    const float* hp = h + (size_t)wid*En;
    const float* rp = res + (size_t)wid*En;
    float v[6]; float ss = 0.f;
    #pragma unroll
    for (int j = 0; j < 6; ++j) {
        int e = lane + j*64;
        float r = hp[e] + rp[e];
        v[j] = r; ss = fmaf(r, r, ss);
    }
    #pragma unroll
    for (int off = 32; off; off >>= 1) ss += __shfl_xor(ss, off, 64);
    float scale = rsqrtf(ss * (1.f/(float)En) + 1e-5f);
    #pragma unroll
    for (int j = 0; j < 6; ++j) {
        int e = lane + j*64;
        out[(size_t)wid*En + e] = v[j] * scale * w[e];
    }
}

extern "C" void kernel_launch(void* const* d_in, const int* in_sizes, int n_in,
                              void* d_out, int out_size, void* d_ws, size_t ws_size,
                              hipStream_t stream)
{
    const float* x         = (const float*)d_in[0];
    const float* patch_w   = (const float*)d_in[1];
    const float* patch_b   = (const float*)d_in[2];
    const float* pos_embed = (const float*)d_in[3];
    const float* in_proj_w = (const float*)d_in[4];
    const float* conv_w    = (const float*)d_in[5];
    const float* conv_b    = (const float*)d_in[6];
    const float* xproj_w   = (const float*)d_in[7];
    const float* dtproj_w  = (const float*)d_in[8];
    const float* dtproj_b  = (const float*)d_in[9];
    const float* A_log     = (const float*)d_in[10];
    const float* D_param   = (const float*)d_in[11];
    const float* outproj_w = (const float*)d_in[12];
    const float* norm_w    = (const float*)d_in[13];
    const float* conv_wb   = (const float*)d_in[14];
    const float* conv_bb   = (const float*)d_in[15];
    const float* xproj_wb  = (const float*)d_in[16];
    const float* dtproj_wb = (const float*)d_in[17];
    const float* dtproj_bb = (const float*)d_in[18];
    const float* A_log_b   = (const float*)d_in[19];
    const float* D_b       = (const float*)d_in[20];
    const float* norm_f_w  = (const float*)d_in[21];

    // ---- carve: fp32 block then bf16 block; total 38.1 MB (<41.5 proven)
    float* pf   = (float*)d_ws;
    float* h    = pf;  pf += (size_t)Mn*En;
    float* res  = pf;  pf += (size_t)Mn*En;
    float* xd   = pf;  pf += (size_t)Mn*40;
    float* Hsum = pf;  pf += (size_t)Bn*NC*Din*Sn;
    float* dtsm = pf;  pf += (size_t)Bn*NC*Din;
    float* hin  = pf;  pf += (size_t)Bn*NC*Din*Sn;
    unsigned short* ub = (unsigned short*)pf;
    unsigned short* xz = ub;  ub += (size_t)Mn*1536;
    unsigned short* yt = ub;  ub += (size_t)Mn*Din;   // hn overlays yt front half
    unsigned short* hn = yt;
    unsigned short* wci = ub; ub += (size_t)DEPTH*1536*En;   // in_proj bf16
    unsigned short* wco = ub; ub += (size_t)DEPTH*En*Din;    // outproj bf16
    unsigned short* wcp = ub; ub += (size_t)En*768;          // patch_w bf16
    unsigned short* pm  = (unsigned short*)Hsum;             // overlay (pre-loop only)
    size_t needed = (size_t)((char*)ub - (char*)d_ws);
    if (ws_size < needed) return;

    const int wave_blocks = (Mn*64)/256;             // 392
    const int B_me   = (Mn*En + 255)/256;
    const int B_md   = (Mn*768 + 255)/256;
    const int B_bd   = (Bn*Din + 255)/256;           // 6
    const int B_bcd  = (Bn*NC*Din + 255)/256;        // 336
    const int mTiles = (Mn + 63)/64;                 // 25

    // ---- weight casts (same work every launch; graph-safe)
    {
        int n4i = DEPTH*1536*En/4, n4o = DEPTH*En*Din/4, n4p = En*768/4;
        cast4<<<(n4i+255)/256, 256, 0, stream>>>(in_proj_w, wci, n4i);
        cast4<<<(n4o+255)/256, 256, 0, stream>>>(outproj_w, wco, n4o);
        cast4<<<(n4p+255)/256, 256, 0, stream>>>(patch_w, wcp, n4p);
    }

    // ---- patch embed: gather(bf16) -> MFMA gemm -> pos/pe epilogue
    k_patch<<<B_md, 256, 0, stream>>>(x, pm);
    dim3 g0(En/64, mTiles);
    gemm_mfma<float><<<g0, 256, 0, stream>>>(pm, wcp, h, En, Mn, En, 768);
    k_posadd<<<B_me, 256, 0, stream>>>(h, patch_b, pos_embed);

    for (int i = 0; i < DEPTH; ++i) {
        rms_residual<<<wave_blocks, 256, 0, stream>>>(h, res, hn, norm_w + (size_t)i*En, i == 0);

        dim3 g1(1536/64, mTiles);
        gemm_mfma<unsigned short><<<g1, 256, 0, stream>>>(
            hn, wci + (size_t)i*1536*En, xz, 1536, Mn, 1536, En);

        const float* cwf = conv_w + (size_t)i*Din*4;
        const float* cbf = conv_b + (size_t)i*Din;
        const float* dwf = dtproj_w + (size_t)i*Din*Rn;
        const float* dbf = dtproj_b + (size_t)i*Din;
        const float* Al  = A_log + (size_t)i*Din*Sn;
        int last = (i >= NSPA);   // no reverse branch follows
        xprojc_k<<<wave_blocks, 256, 0, stream>>>(xz, cwf, cbf,
                                                  xproj_w + (size_t)i*40*Din, xd, 0);
        scanA<<<B_bcd, 256, 0, stream>>>(xz, cwf, cbf, xd, dwf, dbf, Al, Hsum, dtsm, 0);
        scanB<<<B_bd, 256, 0, stream>>>(Al, Hsum, dtsm, hin);
        scanC<<<B_bcd, 256, 0, stream>>>(xz, cwf, cbf, xd, dwf, dbf, Al,
                                         D_param + (size_t)i*Din, hin, yt,
                                         0, 0, last);

        if (!last) {
            const float* cwb = conv_wb + (size_t)i*Din*4;
            const float* cbb = conv_bb + (size_t)i*Din;
            const float* dwb = dtproj_wb + (size_t)i*Din*Rn;
            const float* dbb = dtproj_bb + (size_t)i*Din;
            const float* Alb = A_log_b + (size_t)i*Din*Sn;
            xprojc_k<<<wave_blocks, 256, 0, stream>>>(xz, cwb, cbb,
                                                      xproj_wb + (size_t)i*40*Din, xd, 1);
            scanA<<<B_bcd, 256, 0, stream>>>(xz, cwb, cbb, xd, dwb, dbb, Alb, Hsum, dtsm, 1);
            scanB<<<B_bd, 256, 0, stream>>>(Alb, Hsum, dtsm, hin);
            scanC<<<B_bcd, 256, 0, stream>>>(xz, cwb, cbb, xd, dwb, dbb, Alb,
                                             D_b + (size_t)i*Din, hin, yt,
                                             1, 1, 1);
        }

        dim3 g2(En/64, mTiles);
        gemm_mfma<float><<<g2, 256, 0, stream>>>(
            yt, wco + (size_t)i*En*Din, h, En, Mn, En, Din);
    }

    final_k<<<wave_blocks, 256, 0, stream>>>(h, res, norm_f_w, (float*)d_out);
}

// Round 13
// 2163.788 us; speedup vs baseline: 12.4371x; 1.1201x over previous
//
#include <hip/hip_runtime.h>
#include <hip/hip_bf16.h>
#include <math.h>

// EndoMamba r13: scans restructured — u=silu(conv) precomputed (bf16), NC=98,
// scanB in-place (no hin). bf16 MFMA GEMMs unchanged. fp32 residual backbone.
#define Bn   2
#define Tn   4
#define Nn   196
#define Ln   784
#define Mn   1568
#define En   384
#define Din  768
#define Sn   8
#define Rn   24
#define DEPTH 12
#define NSPA 6
#define NC   98
#define CL   8      // 784 = 98*8

typedef __attribute__((ext_vector_type(8))) short bf16x8;
typedef __attribute__((ext_vector_type(4))) float f32x4;

__device__ __forceinline__ float siluf(float v) { return v / (1.f + __expf(-v)); }
__device__ __forceinline__ float us2f(unsigned short u) {
    union { unsigned int i; float f; } v; v.i = (unsigned)u << 16; return v.f;
}
__device__ __forceinline__ unsigned short f2us(float f) {
    __hip_bfloat16 b = __float2bfloat16(f);
    return *(unsigned short*)&b;
}
__device__ __forceinline__ void cstore(float* p, float v) { *p = v; }
__device__ __forceinline__ void cstore(unsigned short* p, float v) { *p = f2us(v); }

// ------------------------------------------------ fp32 -> bf16 cast (x4)
__global__ __launch_bounds__(256) void cast4(
    const float* __restrict__ src, unsigned short* __restrict__ dst, int n4)
{
    int gid = blockIdx.x*blockDim.x + threadIdx.x;
    if (gid >= n4) return;
    float4 v = *(const float4*)(src + (size_t)gid*4);
    ushort4 o; o.x = f2us(v.x); o.y = f2us(v.y); o.z = f2us(v.z); o.w = f2us(v.w);
    *(ushort4*)(dst + (size_t)gid*4) = o;
}

// ------------------------------------------- patch gather -> pm[m,768] bf16
__global__ __launch_bounds__(256) void k_patch(
    const float* __restrict__ x, unsigned short* __restrict__ pm)
{
    int gid = blockIdx.x*blockDim.x + threadIdx.x;
    if (gid >= Mn*768) return;
    int idx = gid % 768, token = gid / 768;
    int b = token / Ln, l = token % Ln;
    int t = l / Nn, n = l % Nn;
    int hh = n / 14, ww = n % 14;
    int c = idx >> 8, rem = idx & 255, p = rem >> 4, q = rem & 15;
    pm[gid] = f2us(x[(((size_t)(b*3 + c)*Tn + t)*224 + (hh*16 + p))*224 + (ww*16 + q)]);
}

// ------------------------------------- embed epilogue: h += pb + pos + pe
__global__ __launch_bounds__(256) void k_posadd(
    float* __restrict__ h, const float* __restrict__ pb,
    const float* __restrict__ pos)
{
    int gid = blockIdx.x*blockDim.x + threadIdx.x;
    if (gid >= Mn*En) return;
    int e = gid % En, token = gid / En;
    int l = token % Ln;
    int t = l / Nn, n = l % Nn;
    float div = __expf(-logf(10000.f) * (float)(e & ~1) / (float)En);
    float ang = (float)t * div;
    h[gid] += pb[e] + pos[n*En + e] + ((e & 1) ? cosf(ang) : sinf(ang));
}

// ------------------------------------------------------- rmsnorm (+ residual)
__global__ __launch_bounds__(256) void rms_residual(
    const float* __restrict__ hin, float* __restrict__ res,
    unsigned short* __restrict__ hn, const float* __restrict__ w, int first)
{
    int wid  = (blockIdx.x * blockDim.x + threadIdx.x) >> 6;   // token
    int lane = threadIdx.x & 63;
    if (wid >= Mn) return;
    const float* hp = hin + (size_t)wid*En;
    float* rp = res + (size_t)wid*En;
    float v[6]; float ss = 0.f;
    #pragma unroll
    for (int j = 0; j < 6; ++j) {
        int e = lane + j*64;
        float r = first ? hp[e] : (hp[e] + rp[e]);
        v[j] = r; ss = fmaf(r, r, ss);
    }
    #pragma unroll
    for (int off = 32; off; off >>= 1) ss += __shfl_xor(ss, off, 64);
    float scale = rsqrtf(ss * (1.f/(float)En) + 1e-5f);
    #pragma unroll
    for (int j = 0; j < 6; ++j) {
        int e = lane + j*64;
        rp[e] = v[j];
        hn[(size_t)wid*En + e] = f2us(v[j] * scale * w[e]);
    }
}

// ------------------------- bf16 MFMA GEMM: C = A[M,K] * W[N,K]^T
template<typename CT>
__global__ __launch_bounds__(256) void gemm_mfma(
    const unsigned short* __restrict__ A,
    const unsigned short* __restrict__ W,
    CT* __restrict__ C, int ldc, int M, int N, int K)
{
    __shared__ unsigned short As[64][40];   // 32 k + 8 pad
    __shared__ unsigned short Bs[64][40];
    int n0 = blockIdx.x * 64;
    int m0 = blockIdx.y * 64;
    int tid = threadIdx.x;
    int wave = tid >> 6, lane = tid & 63;
    int quad = lane >> 4, fr = lane & 15;
    int arow = tid >> 2;            // 0..63
    int acol = (tid & 3) << 3;      // 0,8,16,24
    f32x4 acc[4] = {};
    for (int k0 = 0; k0 < K; k0 += 32) {
        int mg = m0 + arow; if (mg >= M) mg = M - 1;
        bf16x8 av = *(const bf16x8*)(A + (size_t)mg*K + k0 + acol);
        bf16x8 wv = *(const bf16x8*)(W + (size_t)(n0 + arow)*K + k0 + acol);
        __syncthreads();
        *(bf16x8*)&As[arow][acol] = av;
        *(bf16x8*)&Bs[arow][acol] = wv;
        __syncthreads();
        bf16x8 af = *(const bf16x8*)&As[wave*16 + fr][quad << 3];
        #pragma unroll
        for (int nt = 0; nt < 4; ++nt) {
            bf16x8 bfr = *(const bf16x8*)&Bs[nt*16 + fr][quad << 3];
            acc[nt] = __builtin_amdgcn_mfma_f32_16x16x32_bf16(af, bfr, acc[nt], 0, 0, 0);
        }
    }
    #pragma unroll
    for (int nt = 0; nt < 4; ++nt) {
        #pragma unroll
        for (int r = 0; r < 4; ++r) {
            int mg = m0 + wave*16 + quad*4 + r;
            if (mg < M) cstore(C + (size_t)mg*ldc + n0 + nt*16 + fr, acc[nt][r]);
        }
    }
}

// ------------------- u = silu(conv(xz)) in processed order, bf16 out
__global__ __launch_bounds__(256) void k_conv(
    const unsigned short* __restrict__ xz, const float* __restrict__ cw,
    const float* __restrict__ cb, unsigned short* __restrict__ u, int reverse)
{
    int gid = blockIdx.x*blockDim.x + threadIdx.x;
    if (gid >= Mn*Din) return;
    int d = gid % Din, m = gid / Din;
    int l = m % Ln, b = m / Ln;
    float4 cwv = *(const float4*)(cw + d*4);
    float acc = cb[d];
    #pragma unroll
    for (int k = 0; k < 4; ++k) {
        int ls = l - 3 + k;
        if (ls < 0) continue;
        int lsrc = reverse ? (Ln - 1 - ls) : ls;
        float cwk = (k==0)?cwv.x:(k==1)?cwv.y:(k==2)?cwv.z:cwv.w;
        acc = fmaf(us2f(xz[(size_t)(b*Ln + lsrc)*1536 + d]), cwk, acc);
    }
    u[gid] = f2us(siluf(acc));
}

// ---------------- xproj (768->40) from precomputed u, wave per token
__global__ __launch_bounds__(256) void xproj_u(
    const unsigned short* __restrict__ u, const float* __restrict__ xw,
    float* __restrict__ xd)
{
    int wid  = (blockIdx.x*blockDim.x + threadIdx.x) >> 6;
    int lane = threadIdx.x & 63;
    if (wid >= Mn) return;
    const unsigned short* ur = u + (size_t)wid*Din;
    float v[12];
    #pragma unroll
    for (int j = 0; j < 12; ++j) v[j] = us2f(ur[lane + j*64]);
    for (int e = 0; e < Rn + 2*Sn; ++e) {
        const float* wr = xw + (size_t)e*Din;
        float acc = 0.f;
        #pragma unroll
        for (int j = 0; j < 12; ++j) acc = fmaf(v[j], wr[lane + j*64], acc);
        #pragma unroll
        for (int off = 32; off; off >>= 1) acc += __shfl_xor(acc, off, 64);
        if (lane == 0) xd[(size_t)wid*40 + e] = acc;
    }
}

// ---------------- scan phase A: per-chunk (Sdt, H[8]); dt inline
__global__ __launch_bounds__(256) void scanA(
    const unsigned short* __restrict__ u, const float* __restrict__ xd,
    const float* __restrict__ dw, const float* __restrict__ db,
    const float* __restrict__ A_log,
    float* __restrict__ Hsum, float* __restrict__ dtsum)
{
    int gid = blockIdx.x*blockDim.x + threadIdx.x;
    if (gid >= Bn*NC*Din) return;
    int d = gid % Din;
    int bc = gid / Din;
    int c = bc % NC, b = bc / NC;
    float A[Sn];
    #pragma unroll
    for (int s = 0; s < Sn; ++s) A[s] = -__expf(A_log[d*Sn + s]);
    float dwr[Rn];
    #pragma unroll
    for (int r = 0; r < Rn; ++r) dwr[r] = dw[d*Rn + r];
    float dbv = db[d];
    float hs[Sn] = {0,0,0,0,0,0,0,0};
    float sdt = 0.f;
    int l0 = c*CL;
    const unsigned short* up = u + ((size_t)b*Ln + l0)*Din + d;
    const float* xp = xd + ((size_t)b*Ln + l0)*40;
    #pragma unroll
    for (int l = 0; l < CL; ++l) {
        float uv = us2f(up[(size_t)l*Din]);
        const float* xr = xp + l*40;
        float dta = dbv;
        #pragma unroll
        for (int r = 0; r < Rn; ++r) dta = fmaf(xr[r], dwr[r], dta);
        float dtv = (dta > 20.f) ? dta : log1pf(__expf(dta));
        sdt += dtv;
        const float4* B4 = (const float4*)(xr + Rn);
        float4 Bv0 = B4[0], Bv1 = B4[1];
        float du = dtv * uv;
        hs[0] = fmaf(__expf(dtv*A[0]), hs[0], du*Bv0.x);
        hs[1] = fmaf(__expf(dtv*A[1]), hs[1], du*Bv0.y);
        hs[2] = fmaf(__expf(dtv*A[2]), hs[2], du*Bv0.z);
        hs[3] = fmaf(__expf(dtv*A[3]), hs[3], du*Bv0.w);
        hs[4] = fmaf(__expf(dtv*A[4]), hs[4], du*Bv1.x);
        hs[5] = fmaf(__expf(dtv*A[5]), hs[5], du*Bv1.y);
        hs[6] = fmaf(__expf(dtv*A[6]), hs[6], du*Bv1.z);
        hs[7] = fmaf(__expf(dtv*A[7]), hs[7], du*Bv1.w);
    }
    float4* Hp = (float4*)(Hsum + (size_t)gid*8);
    Hp[0] = make_float4(hs[0], hs[1], hs[2], hs[3]);
    Hp[1] = make_float4(hs[4], hs[5], hs[6], hs[7]);
    dtsum[gid] = sdt;
}

// ---------------- scan phase B: serial fixup, IN-PLACE on Hsum
// after this kernel Hsum[b,c,d] holds the INCOMING state for chunk c.
__global__ __launch_bounds__(256) void scanB(
    const float* __restrict__ A_log, float* __restrict__ Hsum,
    const float* __restrict__ dtsum)
{
    int gid = blockIdx.x*blockDim.x + threadIdx.x;
    if (gid >= Bn*Din) return;
    int d = gid % Din, b = gid / Din;
    float A[Sn];
    #pragma unroll
    for (int s = 0; s < Sn; ++s) A[s] = -__expf(A_log[d*Sn + s]);
    float h[Sn] = {0,0,0,0,0,0,0,0};
    #pragma unroll 7
    for (int c = 0; c < NC; ++c) {
        size_t idx = (size_t)(b*NC + c)*Din + d;
        float4* Hp = (float4*)(Hsum + idx*8);
        float4 H0 = Hp[0], H1 = Hp[1];
        float sdt = dtsum[idx];
        Hp[0] = make_float4(h[0], h[1], h[2], h[3]);
        Hp[1] = make_float4(h[4], h[5], h[6], h[7]);
        h[0] = fmaf(__expf(A[0]*sdt), h[0], H0.x);
        h[1] = fmaf(__expf(A[1]*sdt), h[1], H0.y);
        h[2] = fmaf(__expf(A[2]*sdt), h[2], H0.z);
        h[3] = fmaf(__expf(A[3]*sdt), h[3], H0.w);
        h[4] = fmaf(__expf(A[4]*sdt), h[4], H1.x);
        h[5] = fmaf(__expf(A[5]*sdt), h[5], H1.y);
        h[6] = fmaf(__expf(A[6]*sdt), h[6], H1.z);
        h[7] = fmaf(__expf(A[7]*sdt), h[7], H1.w);
    }
}

// -------- scan phase C: seeded local scan + y emit (+gate); dt inline
// gate: yt = y*silu(z) (accum=0) or yt = (yt_raw + y)*silu(z) (accum=1)
__global__ __launch_bounds__(256) void scanC(
    const unsigned short* __restrict__ u, const float* __restrict__ xd,
    const float* __restrict__ dw, const float* __restrict__ db,
    const float* __restrict__ A_log, const float* __restrict__ Dp,
    const float* __restrict__ hin, const unsigned short* __restrict__ xz,
    unsigned short* __restrict__ y, int reverse, int accum, int gate)
{
    int gid = blockIdx.x*blockDim.x + threadIdx.x;
    if (gid >= Bn*NC*Din) return;
    int d = gid % Din;
    int bc = gid / Din;
    int c = bc % NC, b = bc / NC;
    float A[Sn];
    #pragma unroll
    for (int s = 0; s < Sn; ++s) A[s] = -__expf(A_log[d*Sn + s]);
    float dwr[Rn];
    #pragma unroll
    for (int r = 0; r < Rn; ++r) dwr[r] = dw[d*Rn + r];
    float dbv = db[d];
    const float4* hp = (const float4*)(hin + (size_t)gid*8);
    float4 h0 = hp[0], h1 = hp[1];
    float hs[Sn] = {h0.x, h0.y, h0.z, h0.w, h1.x, h1.y, h1.z, h1.w};
    float Dd = Dp[d];
    int l0 = c*CL;
    const unsigned short* up = u + ((size_t)b*Ln + l0)*Din + d;
    const float* xp = xd + ((size_t)b*Ln + l0)*40;
    unsigned short* yp = y + (size_t)b*Ln*Din + d;
    #pragma unroll
    for (int l = 0; l < CL; ++l) {
        int gl = l0 + l;
        float uv = us2f(up[(size_t)l*Din]);
        const float* xr = xp + l*40;
        float dta = dbv;
        #pragma unroll
        for (int r = 0; r < Rn; ++r) dta = fmaf(xr[r], dwr[r], dta);
        float dtv = (dta > 20.f) ? dta : log1pf(__expf(dta));
        const float4* B4 = (const float4*)(xr + Rn);
        float4 Bv0 = B4[0], Bv1 = B4[1], Cv0 = B4[2], Cv1 = B4[3];
        float du = dtv * uv;
        float yv = 0.f;
        hs[0] = fmaf(__expf(dtv*A[0]), hs[0], du*Bv0.x); yv = fmaf(hs[0], Cv0.x, yv);
        hs[1] = fmaf(__expf(dtv*A[1]), hs[1], du*Bv0.y); yv = fmaf(hs[1], Cv0.y, yv);
        hs[2] = fmaf(__expf(dtv*A[2]), hs[2], du*Bv0.z); yv = fmaf(hs[2], Cv0.z, yv);
        hs[3] = fmaf(__expf(dtv*A[3]), hs[3], du*Bv0.w); yv = fmaf(hs[3], Cv0.w, yv);
        hs[4] = fmaf(__expf(dtv*A[4]), hs[4], du*Bv1.x); yv = fmaf(hs[4], Cv1.x, yv);
        hs[5] = fmaf(__expf(dtv*A[5]), hs[5], du*Bv1.y); yv = fmaf(hs[5], Cv1.y, yv);
        hs[6] = fmaf(__expf(dtv*A[6]), hs[6], du*Bv1.z); yv = fmaf(hs[6], Cv1.z, yv);
        hs[7] = fmaf(__expf(dtv*A[7]), hs[7], du*Bv1.w); yv = fmaf(hs[7], Cv1.w, yv);
        yv = fmaf(uv, Dd, yv);
        int ol = reverse ? (Ln - 1 - gl) : gl;
        unsigned short* dst = yp + (size_t)ol*Din;
        float val = yv;
        if (accum) val += us2f(*dst);
        if (gate) {
            float z = us2f(xz[(size_t)(b*Ln + ol)*1536 + Din + d]);
            val *= siluf(z);
        }
        *dst = f2us(val);
    }
}

// ------------------------------------------------------------- final rmsnorm
__global__ __launch_bounds__(256) void final_k(
    const float* __restrict__ h, const float* __restrict__ res,
    const float* __restrict__ w, float* __restrict__ out)
{
    int wid  = (blockIdx.x * blockDim.x + threadIdx.x) >> 6;
    int lane = threadIdx.x & 63;
    if (wid >= Mn) return;
    const float* hp = h + (size_t)wid*En;
    const float* rp = res + (size_t)wid*En;
    float v[6]; float ss = 0.f;
    #pragma unroll
    for (int j = 0; j < 6; ++j) {
        int e = lane + j*64;
        float r = hp[e] + rp[e];
        v[j] = r; ss = fmaf(r, r, ss);
    }
    #pragma unroll
    for (int off = 32; off; off >>= 1) ss += __shfl_xor(ss, off, 64);
    float scale = rsqrtf(ss * (1.f/(float)En) + 1e-5f);
    #pragma unroll
    for (int j = 0; j < 6; ++j) {
        int e = lane + j*64;
        out[(size_t)wid*En + e] = v[j] * scale * w[e];
    }
}

extern "C" void kernel_launch(void* const* d_in, const int* in_sizes, int n_in,
                              void* d_out, int out_size, void* d_ws, size_t ws_size,
                              hipStream_t stream)
{
    const float* x         = (const float*)d_in[0];
    const float* patch_w   = (const float*)d_in[1];
    const float* patch_b   = (const float*)d_in[2];
    const float* pos_embed = (const float*)d_in[3];
    const float* in_proj_w = (const float*)d_in[4];
    const float* conv_w    = (const float*)d_in[5];
    const float* conv_b    = (const float*)d_in[6];
    const float* xproj_w   = (const float*)d_in[7];
    const float* dtproj_w  = (const float*)d_in[8];
    const float* dtproj_b  = (const float*)d_in[9];
    const float* A_log     = (const float*)d_in[10];
    const float* D_param   = (const float*)d_in[11];
    const float* outproj_w = (const float*)d_in[12];
    const float* norm_w    = (const float*)d_in[13];
    const float* conv_wb   = (const float*)d_in[14];
    const float* conv_bb   = (const float*)d_in[15];
    const float* xproj_wb  = (const float*)d_in[16];
    const float* dtproj_wb = (const float*)d_in[17];
    const float* dtproj_bb = (const float*)d_in[18];
    const float* A_log_b   = (const float*)d_in[19];
    const float* D_b       = (const float*)d_in[20];
    const float* norm_f_w  = (const float*)d_in[21];

    // ---- carve: 39.4 MB total (< 41.4 MB proven by r1)
    float* pf   = (float*)d_ws;
    float* h    = pf;  pf += (size_t)Mn*En;
    float* res  = pf;  pf += (size_t)Mn*En;
    float* xd   = pf;  pf += (size_t)Mn*40;
    float* Hsum = pf;  pf += (size_t)Bn*NC*Din*Sn;   // also hin after scanB
    float* dtsm = pf;  pf += (size_t)Bn*NC*Din;
    unsigned short* ub = (unsigned short*)pf;
    unsigned short* xz = ub;  ub += (size_t)Mn*1536;
    unsigned short* u  = ub;  ub += (size_t)Mn*Din;     // hn overlays u
    unsigned short* hn = u;
    unsigned short* yt = ub;  ub += (size_t)Mn*Din;
    unsigned short* wci = ub; ub += (size_t)DEPTH*1536*En;   // in_proj bf16
    unsigned short* wco = ub; ub += (size_t)DEPTH*En*Din;    // outproj bf16
    unsigned short* wcp = wci;                    // overlay: used pre-loop only
    unsigned short* pm  = (unsigned short*)Hsum;  // overlay: pre-loop only
    size_t needed = (size_t)((char*)ub - (char*)d_ws);
    if (ws_size < needed) return;

    const int wave_blocks = (Mn*64)/256;             // 392
    const int B_me   = (Mn*En + 255)/256;
    const int B_md   = (Mn*768 + 255)/256;           // 4704
    const int B_bd   = (Bn*Din + 255)/256;           // 6
    const int B_bcd  = (Bn*NC*Din + 255)/256;        // 588
    const int mTiles = (Mn + 63)/64;                 // 25

    // ---- patch embed (wcp overlays wci: cast wci AFTER the patch gemm)
    {
        int n4p = En*768/4;
        cast4<<<(n4p+255)/256, 256, 0, stream>>>(patch_w, wcp, n4p);
    }
    k_patch<<<B_md, 256, 0, stream>>>(x, pm);
    dim3 g0(En/64, mTiles);
    gemm_mfma<float><<<g0, 256, 0, stream>>>(pm, wcp, h, En, Mn, En, 768);
    k_posadd<<<B_me, 256, 0, stream>>>(h, patch_b, pos_embed);
    {
        int n4i = DEPTH*1536*En/4, n4o = DEPTH*En*Din/4;
        cast4<<<(n4i+255)/256, 256, 0, stream>>>(in_proj_w, wci, n4i);
        cast4<<<(n4o+255)/256, 256, 0, stream>>>(outproj_w, wco, n4o);
    }

    for (int i = 0; i < DEPTH; ++i) {
        rms_residual<<<wave_blocks, 256, 0, stream>>>(h, res, hn, norm_w + (size_t)i*En, i == 0);

        dim3 g1(1536/64, mTiles);
        gemm_mfma<unsigned short><<<g1, 256, 0, stream>>>(
            hn, wci + (size_t)i*1536*En, xz, 1536, Mn, 1536, En);

        const float* dwf = dtproj_w + (size_t)i*Din*Rn;
        const float* dbf = dtproj_b + (size_t)i*Din;
        const float* Al  = A_log + (size_t)i*Din*Sn;
        int last = (i >= NSPA);
        k_conv<<<B_md, 256, 0, stream>>>(xz, conv_w + (size_t)i*Din*4,
                                         conv_b + (size_t)i*Din, u, 0);
        xproj_u<<<wave_blocks, 256, 0, stream>>>(u, xproj_w + (size_t)i*40*Din, xd);
        scanA<<<B_bcd, 256, 0, stream>>>(u, xd, dwf, dbf, Al, Hsum, dtsm);
        scanB<<<B_bd, 256, 0, stream>>>(Al, Hsum, dtsm);
        scanC<<<B_bcd, 256, 0, stream>>>(u, xd, dwf, dbf, Al,
                                         D_param + (size_t)i*Din, Hsum, xz, yt,
                                         0, 0, last);

        if (!last) {
            const float* dwb = dtproj_wb + (size_t)i*Din*Rn;
            const float* dbb = dtproj_bb + (size_t)i*Din;
            const float* Alb = A_log_b + (size_t)i*Din*Sn;
            k_conv<<<B_md, 256, 0, stream>>>(xz, conv_wb + (size_t)i*Din*4,
                                             conv_bb + (size_t)i*Din, u, 1);
            xproj_u<<<wave_blocks, 256, 0, stream>>>(u, xproj_wb + (size_t)i*40*Din, xd);
            scanA<<<B_bcd, 256, 0, stream>>>(u, xd, dwb, dbb, Alb, Hsum, dtsm);
            scanB<<<B_bd, 256, 0, stream>>>(Alb, Hsum, dtsm);
            scanC<<<B_bcd, 256, 0, stream>>>(u, xd, dwb, dbb, Alb,
                                             D_b + (size_t)i*Din, Hsum, xz, yt,
                                             1, 1, 1);
        }

        dim3 g2(En/64, mTiles);
        gemm_mfma<float><<<g2, 256, 0, stream>>>(
            yt, wco + (size_t)i*En*Din, h, En, Mn, En, Din);
    }

    final_k<<<wave_blocks, 256, 0, stream>>>(h, res, norm_f_w, (float*)d_out);
}

// Round 14
// 1937.646 us; speedup vs baseline: 13.8886x; 1.1167x over previous
//
#include <hip/hip_runtime.h>
#include <hip/hip_bf16.h>
#include <math.h>

// EndoMamba r14: fwd+bwd branch kernels merged (dir from grid), gate folded
// into out_proj GEMM A-staging, fp32 weights converted in GEMM staging
// (no pre-cast). Carve 30.6 MB. bf16 MFMA GEMMs, fp32 residual backbone.
#define Bn   2
#define Tn   4
#define Nn   196
#define Ln   784
#define Mn   1568
#define En   384
#define Din  768
#define Sn   8
#define Rn   24
#define DEPTH 12
#define NSPA 6
#define NC   98
#define CL   8      // 784 = 98*8

typedef __attribute__((ext_vector_type(8))) short bf16x8;
typedef __attribute__((ext_vector_type(4))) float f32x4;

__device__ __forceinline__ float siluf(float v) { return v / (1.f + __expf(-v)); }
__device__ __forceinline__ float us2f(unsigned short u) {
    union { unsigned int i; float f; } v; v.i = (unsigned)u << 16; return v.f;
}
__device__ __forceinline__ unsigned short f2us(float f) {
    __hip_bfloat16 b = __float2bfloat16(f);
    return *(unsigned short*)&b;
}
__device__ __forceinline__ void cstore(float* p, float v) { *p = v; }
__device__ __forceinline__ void cstore(unsigned short* p, float v) { *p = f2us(v); }

// ------------------------------------------- patch gather -> pm[m,768] bf16
__global__ __launch_bounds__(256) void k_patch(
    const float* __restrict__ x, unsigned short* __restrict__ pm)
{
    int gid = blockIdx.x*blockDim.x + threadIdx.x;
    if (gid >= Mn*768) return;
    int idx = gid % 768, token = gid / 768;
    int b = token / Ln, l = token % Ln;
    int t = l / Nn, n = l % Nn;
    int hh = n / 14, ww = n % 14;
    int c = idx >> 8, rem = idx & 255, p = rem >> 4, q = rem & 15;
    pm[gid] = f2us(x[(((size_t)(b*3 + c)*Tn + t)*224 + (hh*16 + p))*224 + (ww*16 + q)]);
}

// ------------------------------------- embed epilogue: h += pb + pos + pe
__global__ __launch_bounds__(256) void k_posadd(
    float* __restrict__ h, const float* __restrict__ pb,
    const float* __restrict__ pos)
{
    int gid = blockIdx.x*blockDim.x + threadIdx.x;
    if (gid >= Mn*En) return;
    int e = gid % En, token = gid / En;
    int l = token % Ln;
    int t = l / Nn, n = l % Nn;
    float div = __expf(-logf(10000.f) * (float)(e & ~1) / (float)En);
    float ang = (float)t * div;
    h[gid] += pb[e] + pos[n*En + e] + ((e & 1) ? cosf(ang) : sinf(ang));
}

// ------------------------------------------------------- rmsnorm (+ residual)
__global__ __launch_bounds__(256) void rms_residual(
    const float* __restrict__ hin, float* __restrict__ res,
    unsigned short* __restrict__ hn, const float* __restrict__ w, int first)
{
    int wid  = (blockIdx.x * blockDim.x + threadIdx.x) >> 6;   // token
    int lane = threadIdx.x & 63;
    if (wid >= Mn) return;
    const float* hp = hin + (size_t)wid*En;
    float* rp = res + (size_t)wid*En;
    float v[6]; float ss = 0.f;
    #pragma unroll
    for (int j = 0; j < 6; ++j) {
        int e = lane + j*64;
        float r = first ? hp[e] : (hp[e] + rp[e]);
        v[j] = r; ss = fmaf(r, r, ss);
    }
    #pragma unroll
    for (int off = 32; off; off >>= 1) ss += __shfl_xor(ss, off, 64);
    float scale = rsqrtf(ss * (1.f/(float)En) + 1e-5f);
    #pragma unroll
    for (int j = 0; j < 6; ++j) {
        int e = lane + j*64;
        rp[e] = v[j];
        hn[(size_t)wid*En + e] = f2us(v[j] * scale * w[e]);
    }
}

// ---------------- bf16 MFMA GEMM: C = A[M,K] * W[N,K]^T, W fp32 (cast in stage)
// GATED: A_eff = (yf + (ndir==2? yb:0)) * silu(z), all bf16 inputs.
template<typename CT, int GATED>
__global__ __launch_bounds__(256) void gemm_mfma(
    const unsigned short* __restrict__ A,     // bf16 A (or yf when GATED)
    const unsigned short* __restrict__ Yb,    // yb (GATED only)
    const unsigned short* __restrict__ Z,     // z base, row stride 1536 (GATED)
    const float* __restrict__ W,
    CT* __restrict__ C, int ldc, int M, int N, int K, int ndir)
{
    __shared__ unsigned short As[64][40];   // 32 k + 8 pad
    __shared__ unsigned short Bs[64][40];
    int n0 = blockIdx.x * 64;
    int m0 = blockIdx.y * 64;
    int tid = threadIdx.x;
    int wave = tid >> 6, lane = tid & 63;
    int quad = lane >> 4, fr = lane & 15;
    int arow = tid >> 2;            // 0..63
    int acol = (tid & 3) << 3;      // 0,8,16,24
    f32x4 acc[4] = {};
    for (int k0 = 0; k0 < K; k0 += 32) {
        int mg = m0 + arow; if (mg >= M) mg = M - 1;
        bf16x8 av;
        if (!GATED) {
            av = *(const bf16x8*)(A + (size_t)mg*K + k0 + acol);
        } else {
            const unsigned short* yf = A  + (size_t)mg*K + k0 + acol;
            const unsigned short* yb = Yb + (size_t)mg*K + k0 + acol;
            const unsigned short* zp = Z  + (size_t)mg*1536 + k0 + acol;
            ushort4 f0 = *(const ushort4*)yf, f1 = *(const ushort4*)(yf+4);
            ushort4 b0 = *(const ushort4*)yb, b1 = *(const ushort4*)(yb+4);
            ushort4 z0 = *(const ushort4*)zp, z1 = *(const ushort4*)(zp+4);
            unsigned short o[8];
            const unsigned short* fu = (const unsigned short*)&f0;
            const unsigned short* bu = (const unsigned short*)&b0;
            const unsigned short* zu = (const unsigned short*)&z0;
            #pragma unroll
            for (int j = 0; j < 4; ++j) {
                float v = us2f(fu[j]);
                if (ndir == 2) v += us2f(bu[j]);
                o[j] = f2us(v * siluf(us2f(zu[j])));
            }
            fu = (const unsigned short*)&f1; bu = (const unsigned short*)&b1;
            zu = (const unsigned short*)&z1;
            #pragma unroll
            for (int j = 0; j < 4; ++j) {
                float v = us2f(fu[j]);
                if (ndir == 2) v += us2f(bu[j]);
                o[4+j] = f2us(v * siluf(us2f(zu[j])));
            }
            av = *(bf16x8*)o;
        }
        // W fp32 -> bf16 in registers
        float4 w0 = *(const float4*)(W + (size_t)(n0 + arow)*K + k0 + acol);
        float4 w1 = *(const float4*)(W + (size_t)(n0 + arow)*K + k0 + acol + 4);
        unsigned short wv[8];
        wv[0]=f2us(w0.x); wv[1]=f2us(w0.y); wv[2]=f2us(w0.z); wv[3]=f2us(w0.w);
        wv[4]=f2us(w1.x); wv[5]=f2us(w1.y); wv[6]=f2us(w1.z); wv[7]=f2us(w1.w);
        __syncthreads();
        *(bf16x8*)&As[arow][acol] = av;
        *(bf16x8*)&Bs[arow][acol] = *(bf16x8*)wv;
        __syncthreads();
        bf16x8 af = *(const bf16x8*)&As[wave*16 + fr][quad << 3];
        #pragma unroll
        for (int nt = 0; nt < 4; ++nt) {
            bf16x8 bfr = *(const bf16x8*)&Bs[nt*16 + fr][quad << 3];
            acc[nt] = __builtin_amdgcn_mfma_f32_16x16x32_bf16(af, bfr, acc[nt], 0, 0, 0);
        }
    }
    #pragma unroll
    for (int nt = 0; nt < 4; ++nt) {
        #pragma unroll
        for (int r = 0; r < 4; ++r) {
            int mg = m0 + wave*16 + quad*4 + r;
            if (mg < M) cstore(C + (size_t)mg*ldc + n0 + nt*16 + fr, acc[nt][r]);
        }
    }
}

// ------ u = silu(conv(xz)) both dirs in one launch: u[dir][m][d] bf16
__global__ __launch_bounds__(256) void k_conv2(
    const unsigned short* __restrict__ xz,
    const float* __restrict__ cwf, const float* __restrict__ cbf,
    const float* __restrict__ cwb, const float* __restrict__ cbb,
    unsigned short* __restrict__ u, int ndir)
{
    int gid = blockIdx.x*blockDim.x + threadIdx.x;
    if (gid >= ndir*Mn*Din) return;
    int dir = gid / (Mn*Din);
    int rem = gid % (Mn*Din);
    int d = rem % Din, m = rem / Din;
    int l = m % Ln, b = m / Ln;
    const float* cw = dir ? cwb : cwf;
    const float* cb = dir ? cbb : cbf;
    float4 cwv = *(const float4*)(cw + d*4);
    float acc = cb[d];
    #pragma unroll
    for (int k = 0; k < 4; ++k) {
        int ls = l - 3 + k;
        if (ls < 0) continue;
        int lsrc = dir ? (Ln - 1 - ls) : ls;
        float cwk = (k==0)?cwv.x:(k==1)?cwv.y:(k==2)?cwv.z:cwv.w;
        acc = fmaf(us2f(xz[(size_t)(b*Ln + lsrc)*1536 + d]), cwk, acc);
    }
    u[gid] = f2us(siluf(acc));
}

// ---------------- xproj (768->40) both dirs, wave per (dir, token)
__global__ __launch_bounds__(256) void xproj2(
    const unsigned short* __restrict__ u,
    const float* __restrict__ xwf, const float* __restrict__ xwb,
    float* __restrict__ xd, int ndir)
{
    int wid  = (blockIdx.x*blockDim.x + threadIdx.x) >> 6;
    int lane = threadIdx.x & 63;
    if (wid >= ndir*Mn) return;
    int dir = wid / Mn, m = wid % Mn;
    const float* xw = dir ? xwb : xwf;
    const unsigned short* ur = u + (size_t)dir*Mn*Din + (size_t)m*Din;
    float v[12];
    #pragma unroll
    for (int j = 0; j < 12; ++j) v[j] = us2f(ur[lane + j*64]);
    for (int e = 0; e < Rn + 2*Sn; ++e) {
        const float* wr = xw + (size_t)e*Din;
        float acc = 0.f;
        #pragma unroll
        for (int j = 0; j < 12; ++j) acc = fmaf(v[j], wr[lane + j*64], acc);
        #pragma unroll
        for (int off = 32; off; off >>= 1) acc += __shfl_xor(acc, off, 64);
        if (lane == 0) xd[(size_t)wid*40 + e] = acc;   // xd[dir][m][40]
    }
}

// ---------------- scan phase A: per-chunk (Sdt, H[8]); dt inline; both dirs
__global__ __launch_bounds__(256) void scanA(
    const unsigned short* __restrict__ u, const float* __restrict__ xd,
    const float* __restrict__ dwf, const float* __restrict__ dbf,
    const float* __restrict__ dwb, const float* __restrict__ dbb,
    const float* __restrict__ Alf, const float* __restrict__ Alb,
    float* __restrict__ Hsum, float* __restrict__ dtsum, int ndir)
{
    int gid = blockIdx.x*blockDim.x + threadIdx.x;
    if (gid >= ndir*Bn*NC*Din) return;
    int dir = gid / (Bn*NC*Din);
    int rem = gid % (Bn*NC*Din);
    int d = rem % Din;
    int bc = rem / Din;
    int c = bc % NC, b = bc / NC;
    const float* A_log = dir ? Alb : Alf;
    const float* dw = dir ? dwb : dwf;
    const float* db = dir ? dbb : dbf;
    float A[Sn];
    #pragma unroll
    for (int s = 0; s < Sn; ++s) A[s] = -__expf(A_log[d*Sn + s]);
    float dwr[Rn];
    #pragma unroll
    for (int r = 0; r < Rn; ++r) dwr[r] = dw[d*Rn + r];
    float dbv = db[d];
    float hs[Sn] = {0,0,0,0,0,0,0,0};
    float sdt = 0.f;
    int l0 = c*CL;
    const unsigned short* up = u + (size_t)dir*Mn*Din + ((size_t)b*Ln + l0)*Din + d;
    const float* xp = xd + (size_t)dir*Mn*40 + ((size_t)b*Ln + l0)*40;
    #pragma unroll
    for (int l = 0; l < CL; ++l) {
        float uv = us2f(up[(size_t)l*Din]);
        const float* xr = xp + l*40;
        float dta = dbv;
        #pragma unroll
        for (int r = 0; r < Rn; ++r) dta = fmaf(xr[r], dwr[r], dta);
        float dtv = (dta > 20.f) ? dta : log1pf(__expf(dta));
        sdt += dtv;
        const float4* B4 = (const float4*)(xr + Rn);
        float4 Bv0 = B4[0], Bv1 = B4[1];
        float du = dtv * uv;
        hs[0] = fmaf(__expf(dtv*A[0]), hs[0], du*Bv0.x);
        hs[1] = fmaf(__expf(dtv*A[1]), hs[1], du*Bv0.y);
        hs[2] = fmaf(__expf(dtv*A[2]), hs[2], du*Bv0.z);
        hs[3] = fmaf(__expf(dtv*A[3]), hs[3], du*Bv0.w);
        hs[4] = fmaf(__expf(dtv*A[4]), hs[4], du*Bv1.x);
        hs[5] = fmaf(__expf(dtv*A[5]), hs[5], du*Bv1.y);
        hs[6] = fmaf(__expf(dtv*A[6]), hs[6], du*Bv1.z);
        hs[7] = fmaf(__expf(dtv*A[7]), hs[7], du*Bv1.w);
    }
    float4* Hp = (float4*)(Hsum + (size_t)gid*8);
    Hp[0] = make_float4(hs[0], hs[1], hs[2], hs[3]);
    Hp[1] = make_float4(hs[4], hs[5], hs[6], hs[7]);
    dtsum[gid] = sdt;
}

// ---------------- scan phase B: serial fixup IN-PLACE on Hsum, both dirs
__global__ __launch_bounds__(256) void scanB(
    const float* __restrict__ Alf, const float* __restrict__ Alb,
    float* __restrict__ Hsum, const float* __restrict__ dtsum, int ndir)
{
    int gid = blockIdx.x*blockDim.x + threadIdx.x;
    if (gid >= ndir*Bn*Din) return;
    int dir = gid / (Bn*Din);
    int rem = gid % (Bn*Din);
    int d = rem % Din, b = rem / Din;
    const float* A_log = dir ? Alb : Alf;
    float A[Sn];
    #pragma unroll
    for (int s = 0; s < Sn; ++s) A[s] = -__expf(A_log[d*Sn + s]);
    float h[Sn] = {0,0,0,0,0,0,0,0};
    size_t base = (size_t)dir*Bn*NC*Din;
    #pragma unroll 7
    for (int c = 0; c < NC; ++c) {
        size_t idx = base + (size_t)(b*NC + c)*Din + d;
        float4* Hp = (float4*)(Hsum + idx*8);
        float4 H0 = Hp[0], H1 = Hp[1];
        float sdt = dtsum[idx];
        Hp[0] = make_float4(h[0], h[1], h[2], h[3]);
        Hp[1] = make_float4(h[4], h[5], h[6], h[7]);
        h[0] = fmaf(__expf(A[0]*sdt), h[0], H0.x);
        h[1] = fmaf(__expf(A[1]*sdt), h[1], H0.y);
        h[2] = fmaf(__expf(A[2]*sdt), h[2], H0.z);
        h[3] = fmaf(__expf(A[3]*sdt), h[3], H0.w);
        h[4] = fmaf(__expf(A[4]*sdt), h[4], H1.x);
        h[5] = fmaf(__expf(A[5]*sdt), h[5], H1.y);
        h[6] = fmaf(__expf(A[6]*sdt), h[6], H1.z);
        h[7] = fmaf(__expf(A[7]*sdt), h[7], H1.w);
    }
}

// -------- scan phase C: seeded local scan, raw y emit (no gate), both dirs
// bwd writes to un-reversed index, so yt[dir] is direction-aligned.
__global__ __launch_bounds__(256) void scanC(
    const unsigned short* __restrict__ u, const float* __restrict__ xd,
    const float* __restrict__ dwf, const float* __restrict__ dbf,
    const float* __restrict__ dwb, const float* __restrict__ dbb,
    const float* __restrict__ Alf, const float* __restrict__ Alb,
    const float* __restrict__ Dpf, const float* __restrict__ Dpb,
    const float* __restrict__ Hsum, unsigned short* __restrict__ yt, int ndir)
{
    int gid = blockIdx.x*blockDim.x + threadIdx.x;
    if (gid >= ndir*Bn*NC*Din) return;
    int dir = gid / (Bn*NC*Din);
    int rem = gid % (Bn*NC*Din);
    int d = rem % Din;
    int bc = rem / Din;
    int c = bc % NC, b = bc / NC;
    const float* A_log = dir ? Alb : Alf;
    const float* dw = dir ? dwb : dwf;
    const float* db = dir ? dbb : dbf;
    const float* Dp = dir ? Dpb : Dpf;
    float A[Sn];
    #pragma unroll
    for (int s = 0; s < Sn; ++s) A[s] = -__expf(A_log[d*Sn + s]);
    float dwr[Rn];
    #pragma unroll
    for (int r = 0; r < Rn; ++r) dwr[r] = dw[d*Rn + r];
    float dbv = db[d];
    const float4* hp = (const float4*)(Hsum + (size_t)gid*8);
    float4 h0 = hp[0], h1 = hp[1];
    float hs[Sn] = {h0.x, h0.y, h0.z, h0.w, h1.x, h1.y, h1.z, h1.w};
    float Dd = Dp[d];
    int l0 = c*CL;
    const unsigned short* up = u + (size_t)dir*Mn*Din + ((size_t)b*Ln + l0)*Din + d;
    const float* xp = xd + (size_t)dir*Mn*40 + ((size_t)b*Ln + l0)*40;
    unsigned short* yp = yt + (size_t)dir*Mn*Din + (size_t)b*Ln*Din + d;
    #pragma unroll
    for (int l = 0; l < CL; ++l) {
        int gl = l0 + l;
        float uv = us2f(up[(size_t)l*Din]);
        const float* xr = xp + l*40;
        float dta = dbv;
        #pragma unroll
        for (int r = 0; r < Rn; ++r) dta = fmaf(xr[r], dwr[r], dta);
        float dtv = (dta > 20.f) ? dta : log1pf(__expf(dta));
        const float4* B4 = (const float4*)(xr + Rn);
        float4 Bv0 = B4[0], Bv1 = B4[1], Cv0 = B4[2], Cv1 = B4[3];
        float du = dtv * uv;
        float yv = 0.f;
        hs[0] = fmaf(__expf(dtv*A[0]), hs[0], du*Bv0.x); yv = fmaf(hs[0], Cv0.x, yv);
        hs[1] = fmaf(__expf(dtv*A[1]), hs[1], du*Bv0.y); yv = fmaf(hs[1], Cv0.y, yv);
        hs[2] = fmaf(__expf(dtv*A[2]), hs[2], du*Bv0.z); yv = fmaf(hs[2], Cv0.z, yv);
        hs[3] = fmaf(__expf(dtv*A[3]), hs[3], du*Bv0.w); yv = fmaf(hs[3], Cv0.w, yv);
        hs[4] = fmaf(__expf(dtv*A[4]), hs[4], du*Bv1.x); yv = fmaf(hs[4], Cv1.x, yv);
        hs[5] = fmaf(__expf(dtv*A[5]), hs[5], du*Bv1.y); yv = fmaf(hs[5], Cv1.y, yv);
        hs[6] = fmaf(__expf(dtv*A[6]), hs[6], du*Bv1.z); yv = fmaf(hs[6], Cv1.z, yv);
        hs[7] = fmaf(__expf(dtv*A[7]), hs[7], du*Bv1.w); yv = fmaf(hs[7], Cv1.w, yv);
        yv = fmaf(uv, Dd, yv);
        int ol = dir ? (Ln - 1 - gl) : gl;
        yp[(size_t)ol*Din] = f2us(yv);
    }
}

// ------------------------------------------------------------- final rmsnorm
__global__ __launch_bounds__(256) void final_k(
    const float* __restrict__ h, const float* __restrict__ res,
    const float* __restrict__ w, float* __restrict__ out)
{
    int wid  = (blockIdx.x * blockDim.x + threadIdx.x) >> 6;
    int lane = threadIdx.x & 63;
    if (wid >= Mn) return;
    const float* hp = h + (size_t)wid*En;
    const float* rp = res + (size_t)wid*En;
    float v[6]; float ss = 0.f;
    #pragma unroll
    for (int j = 0; j < 6; ++j) {
        int e = lane + j*64;
        float r = hp[e] + rp[e];
        v[j] = r; ss = fmaf(r, r, ss);
    }
    #pragma unroll
    for (int off = 32; off; off >>= 1) ss += __shfl_xor(ss, off, 64);
    float scale = rsqrtf(ss * (1.f/(float)En) + 1e-5f);
    #pragma unroll
    for (int j = 0; j < 6; ++j) {
        int e = lane + j*64;
        out[(size_t)wid*En + e] = v[j] * scale * w[e];
    }
}

extern "C" void kernel_launch(void* const* d_in, const int* in_sizes, int n_in,
                              void* d_out, int out_size, void* d_ws, size_t ws_size,
                              hipStream_t stream)
{
    const float* x         = (const float*)d_in[0];
    const float* patch_w   = (const float*)d_in[1];
    const float* patch_b   = (const float*)d_in[2];
    const float* pos_embed = (const float*)d_in[3];
    const float* in_proj_w = (const float*)d_in[4];
    const float* conv_w    = (const float*)d_in[5];
    const float* conv_b    = (const float*)d_in[6];
    const float* xproj_w   = (const float*)d_in[7];
    const float* dtproj_w  = (const float*)d_in[8];
    const float* dtproj_b  = (const float*)d_in[9];
    const float* A_log     = (const float*)d_in[10];
    const float* D_param   = (const float*)d_in[11];
    const float* outproj_w = (const float*)d_in[12];
    const float* norm_w    = (const float*)d_in[13];
    const float* conv_wb   = (const float*)d_in[14];
    const float* conv_bb   = (const float*)d_in[15];
    const float* xproj_wb  = (const float*)d_in[16];
    const float* dtproj_wb = (const float*)d_in[17];
    const float* dtproj_bb = (const float*)d_in[18];
    const float* A_log_b   = (const float*)d_in[19];
    const float* D_b       = (const float*)d_in[20];
    const float* norm_f_w  = (const float*)d_in[21];

    // ---- carve: 30.6 MB total (< 41.5 MB proven)
    float* pf   = (float*)d_ws;
    float* h    = pf;  pf += (size_t)Mn*En;
    float* res  = pf;  pf += (size_t)Mn*En;
    float* xd   = pf;  pf += (size_t)2*Mn*40;          // [dir][m][40]
    float* Hsum = pf;  pf += (size_t)2*Bn*NC*Din*Sn;   // [dir][b][c][d][8]
    float* dtsm = pf;  pf += (size_t)2*Bn*NC*Din;
    unsigned short* ub = (unsigned short*)pf;
    unsigned short* xz = ub;  ub += (size_t)Mn*1536;
    unsigned short* u  = ub;  ub += (size_t)2*Mn*Din;   // [dir][m][d]; hn overlays
    unsigned short* hn = u;
    unsigned short* yt = ub;  ub += (size_t)2*Mn*Din;   // [dir][m][d]
    unsigned short* pm = (unsigned short*)Hsum;         // overlay: pre-loop only
    size_t needed = (size_t)((char*)ub - (char*)d_ws);
    if (ws_size < needed) return;

    const int wave_blocks = (Mn*64)/256;             // 392
    const int B_me   = (Mn*En + 255)/256;
    const int B_md   = (Mn*768 + 255)/256;           // 4704
    const int mTiles = (Mn + 63)/64;                 // 25

    // ---- patch embed: gather(bf16) -> MFMA gemm (fp32 W) -> pos/pe epilogue
    k_patch<<<B_md, 256, 0, stream>>>(x, pm);
    dim3 g0(En/64, mTiles);
    gemm_mfma<float,0><<<g0, 256, 0, stream>>>(pm, nullptr, nullptr, patch_w,
                                               h, En, Mn, En, 768, 1);
    k_posadd<<<B_me, 256, 0, stream>>>(h, patch_b, pos_embed);

    for (int i = 0; i < DEPTH; ++i) {
        int ndir = (i < NSPA) ? 2 : 1;
        rms_residual<<<wave_blocks, 256, 0, stream>>>(h, res, hn, norm_w + (size_t)i*En, i == 0);

        dim3 g1(1536/64, mTiles);
        gemm_mfma<unsigned short,0><<<g1, 256, 0, stream>>>(
            hn, nullptr, nullptr, in_proj_w + (size_t)i*1536*En,
            xz, 1536, Mn, 1536, En, 1);

        const float* cwf = conv_w + (size_t)i*Din*4;
        const float* cbf = conv_b + (size_t)i*Din;
        const float* dwf = dtproj_w + (size_t)i*Din*Rn;
        const float* dbf = dtproj_b + (size_t)i*Din;
        const float* Alf = A_log + (size_t)i*Din*Sn;
        const float* Dpf = D_param + (size_t)i*Din;
        const float* cwb = conv_wb + (size_t)i*Din*4;
        const float* cbb = conv_bb + (size_t)i*Din;
        const float* dwb = dtproj_wb + (size_t)i*Din*Rn;
        const float* dbb = dtproj_bb + (size_t)i*Din;
        const float* Alb = A_log_b + (size_t)i*Din*Sn;
        const float* Dpb = D_b + (size_t)i*Din;
        const float* xwf = xproj_w + (size_t)i*40*Din;
        const float* xwb = xproj_wb + (size_t)i*40*Din;

        int c_blocks  = (ndir*Mn*Din + 255)/256;
        int xp_blocks = (ndir*Mn*64 + 255)/256;
        int sA_blocks = (ndir*Bn*NC*Din + 255)/256;
        int sB_blocks = (ndir*Bn*Din + 255)/256;

        k_conv2<<<c_blocks, 256, 0, stream>>>(xz, cwf, cbf, cwb, cbb, u, ndir);
        xproj2<<<xp_blocks, 256, 0, stream>>>(u, xwf, xwb, xd, ndir);
        scanA<<<sA_blocks, 256, 0, stream>>>(u, xd, dwf, dbf, dwb, dbb,
                                             Alf, Alb, Hsum, dtsm, ndir);
        scanB<<<sB_blocks, 256, 0, stream>>>(Alf, Alb, Hsum, dtsm, ndir);
        scanC<<<sA_blocks, 256, 0, stream>>>(u, xd, dwf, dbf, dwb, dbb,
                                             Alf, Alb, Dpf, Dpb, Hsum, yt, ndir);

        dim3 g2(En/64, mTiles);
        gemm_mfma<float,1><<<g2, 256, 0, stream>>>(
            yt, yt + (size_t)Mn*Din, xz + Din, outproj_w + (size_t)i*En*Din,
            h, En, Mn, En, Din, ndir);
    }

    final_k<<<wave_blocks, 256, 0, stream>>>(h, res, norm_f_w, (float*)d_out);
}